// Round 11
// baseline (208.446 us; speedup 1.0000x reference)
//
#include <hip/hip_runtime.h>
#include <hip/hip_bf16.h>
#include <math.h>

#define NROWS 16384
#define DM    2048
#define RK    16
#define LRc    1e-3f
#define L2c    1e-4f
#define MOMc   0.9f
#define SCALEc 0.1f
#define LNEPS  1e-5f

typedef __attribute__((ext_vector_type(8))) short short8;
typedef __attribute__((ext_vector_type(4))) float floatx4;

union U4S8 { uint4 u4; short8 s8; unsigned u[4]; };

__device__ inline unsigned pk2(float lo, float hi) {
    union { __hip_bfloat162 h; unsigned u; } cv;
    cv.h = __float22bfloat162_rn(make_float2(lo, hi));
    return cv.u;
}

// direct global->LDS DMA, 16B per lane, NT cache policy (streamed-once data)
__device__ __forceinline__ void gld16nt(const float* g, float* l) {
    __builtin_amdgcn_global_load_lds(
        (const __attribute__((address_space(1))) unsigned*)g,
        (__attribute__((address_space(3))) unsigned*)l,
        16, 0, 2 /* NT */);
}

// ---------------------------------------------------------------------------
// k_prep: blocks 0-15: BtB/CtC (atomic). blocks 16-31: pack B,C,D∘B into
// MFMA fragment layout. block 32: D!=0 flag.
// ---------------------------------------------------------------------------
__global__ __launch_bounds__(256) void k_prep(
    const float* __restrict__ B, const float* __restrict__ C,
    const float* __restrict__ Dd,
    float* __restrict__ BtB, float* __restrict__ CtC,
    uint4* __restrict__ Cpk, uint4* __restrict__ Bpk, uint4* __restrict__ DBpk,
    int* __restrict__ flag)
{
    const int bid = blockIdx.x, t = threadIdx.x;
    if (bid < 16) {
        const int a = t >> 4, b = t & 15;
        const int dBeg = bid * 128;
        float sc = 0.f, sb = 0.f;
        for (int d = dBeg; d < dBeg + 128; ++d) {
            sc += C[d * RK + a] * C[d * RK + b];
            sb += B[d * RK + a] * B[d * RK + b];
        }
        atomicAdd(CtC + a * RK + b, sc);
        atomicAdd(BtB + a * RK + b, sb);
    } else if (bid < 32) {
        const int idx = (bid - 16) * 256 + t;      // 4096 = 64 chunks x 64 lanes
        const int c = idx >> 6, l = idx & 63;
        const int dbase = c * 32 + (l >> 4) * 8;
        const int col = l & 15;
        U4S8 uc, ub, ud;
        #pragma unroll
        for (int q = 0; q < 4; ++q) {
            const int d0 = dbase + 2 * q, d1 = d0 + 1;
            uc.u[q] = pk2(C[d0 * RK + col], C[d1 * RK + col]);
            ub.u[q] = pk2(B[d0 * RK + col], B[d1 * RK + col]);
            ud.u[q] = pk2(Dd[d0] * B[d0 * RK + col], Dd[d1] * B[d1 * RK + col]);
        }
        Cpk[idx] = uc.u4; Bpk[idx] = ub.u4; DBpk[idx] = ud.u4;
    } else {
        __shared__ int sh;
        if (t == 0) sh = 0;
        __syncthreads();
        int any = 0;
        for (int i = t; i < DM; i += 256) any |= (Dd[i] != 0.f) ? 1 : 0;
        if (any) sh = 1;
        __syncthreads();
        if (t == 0) *flag = sh;
    }
}

// ---------------------------------------------------------------------------
// k_A: LDS-staged MFMA row-reductions. Load order per chunk: frag loads
// FIRST, then NT staging of chunk c+1, then sched_barrier(0) so the compiler
// cannot sink the loads. Waiting on frags = vmcnt(4) -> staging stays in
// flight through the MFMAs; only the trailing __syncthreads drains it.
// Block = 16 rows x 1024 d (half), 4 waves, 8 chunks, 32 KB LDS dbuf.
//   kC = k@C, vB = v@B, kDB = (k o D)@B (skipped when D==0) -> partials.
// 2048 blocks x 256 thr.
// ---------------------------------------------------------------------------
__global__ __launch_bounds__(256) void k_A(
    const float* __restrict__ k, const float* __restrict__ v,
    const uint4* __restrict__ Cpk, const uint4* __restrict__ Bpk,
    const uint4* __restrict__ DBpk, const int* __restrict__ flag,
    float* __restrict__ kCp, float* __restrict__ vBp, float* __restrict__ kDBp)
{
    __shared__ float kt[2][2][2048];   // [buf][k/v][16 rows * 128 floats] 32 KB
    const int t = threadIdx.x;
    const int lane = t & 63;
    const int w = t >> 6;
    const int rowgrp = blockIdx.x >> 1;
    const int half = blockIdx.x & 1;
    const int R0 = rowgrp * 16;
    const int dbase = half * 1024;
    const int m = lane & 15;
    const int g = lane >> 4;
    const int dnz = *flag;

    // staging lane geometry: instr j covers rows 2j,2j+1 (srow), 32 blks/row
    const int srow = lane >> 5;        // 0..1
    const int sblk = lane & 31;        // physical 16B-block within row

    floatx4 a0 = {0.f,0.f,0.f,0.f}, a1 = {0.f,0.f,0.f,0.f}, a2 = {0.f,0.f,0.f,0.f};

    #define STAGE_A(c_, buf_) {                                                \
        _Pragma("unroll")                                                      \
        for (int jj = 0; jj < 2; ++jj) {                                       \
            const int j = 2 * w + jj;                                          \
            const int row = 2 * j + srow;                                      \
            const int col = dbase + (c_) * 128 + 4 * (sblk ^ (row & 15));      \
            gld16nt(k + (size_t)(R0 + row) * DM + col, &kt[buf_][0][j * 256]); \
            gld16nt(v + (size_t)(R0 + row) * DM + col, &kt[buf_][1][j * 256]); \
        } }

    // prologue: stage chunk 0 into buf 0
    STAGE_A(0, 0);
    __syncthreads();

    for (int c = 0; c < 8; ++c) {
        const int buf = c & 1;

        // frag loads FIRST (older in vmcnt order than staging)
        const int cc = half * 32 + c * 4 + w;        // 32-d K-slice index
        uint4 cf = Cpk[cc * 64 + lane];
        uint4 bf = Bpk[cc * 64 + lane];
        uint4 df = make_uint4(0u,0u,0u,0u);
        if (dnz) df = DBpk[cc * 64 + lane];

        if (c + 1 < 8) {       // NT staging of next chunk (younger: stays in flight)
            STAGE_A(c + 1, buf ^ 1);
        }
        __builtin_amdgcn_sched_barrier(0);           // don't sink loads below

        // swizzled ds_read: logical blocks (w*8+2g), (w*8+2g+1)
        const int b0 = (w * 8 + 2 * g) ^ m;
        const int b1 = b0 ^ 1;
        const float4 kx = *(const float4*)&kt[buf][0][m * 128 + b0 * 4];
        const float4 ky = *(const float4*)&kt[buf][0][m * 128 + b1 * 4];
        const float4 vx = *(const float4*)&kt[buf][1][m * 128 + b0 * 4];
        const float4 vy = *(const float4*)&kt[buf][1][m * 128 + b1 * 4];

        U4S8 kf, vf, cu, bu, du;
        kf.u[0] = pk2(kx.x, kx.y); kf.u[1] = pk2(kx.z, kx.w);
        kf.u[2] = pk2(ky.x, ky.y); kf.u[3] = pk2(ky.z, ky.w);
        vf.u[0] = pk2(vx.x, vx.y); vf.u[1] = pk2(vx.z, vx.w);
        vf.u[2] = pk2(vy.x, vy.y); vf.u[3] = pk2(vy.z, vy.w);
        cu.u4 = cf; bu.u4 = bf; du.u4 = df;

        a0 = __builtin_amdgcn_mfma_f32_16x16x32_bf16(kf.s8, cu.s8, a0, 0, 0, 0);
        a1 = __builtin_amdgcn_mfma_f32_16x16x32_bf16(vf.s8, bu.s8, a1, 0, 0, 0);
        if (dnz)
            a2 = __builtin_amdgcn_mfma_f32_16x16x32_bf16(kf.s8, du.s8, a2, 0, 0, 0);

        __syncthreads();   // drains staging; protects buf swap
    }
    #undef STAGE_A

    // cross-wave K-reduce: reuse kt LDS as floatx4[3][4][64] (12 KB < 32 KB)
    floatx4* red = (floatx4*)&kt[0][0][0];
    red[(0 * 4 + w) * 64 + lane] = a0;
    red[(1 * 4 + w) * 64 + lane] = a1;
    red[(2 * 4 + w) * 64 + lane] = a2;
    __syncthreads();
    if (w == 0) {
        const floatx4 s0 = red[0*256+0*64+lane] + red[0*256+1*64+lane]
                         + red[0*256+2*64+lane] + red[0*256+3*64+lane];
        const floatx4 s1 = red[1*256+0*64+lane] + red[1*256+1*64+lane]
                         + red[1*256+2*64+lane] + red[1*256+3*64+lane];
        const floatx4 s2 = red[2*256+0*64+lane] + red[2*256+1*64+lane]
                         + red[2*256+2*64+lane] + red[2*256+3*64+lane];
        const size_t H = (size_t)half * NROWS * RK;
        #pragma unroll
        for (int j = 0; j < 4; ++j) {
            const size_t o = H + (size_t)(R0 + g * 4 + j) * RK + m;
            kCp[o] = s0[j];
            vBp[o] = s1[j];
            if (dnz) kDBp[o] = s2[j];
        }
    }
}

// ---------------------------------------------------------------------------
// k_mid: sum halves; errB = vB - kDB - 0.1*kC@BtB. Writes kC_g, eB_g.
// ---------------------------------------------------------------------------
__global__ __launch_bounds__(256) void k_mid(
    const float* __restrict__ kCp, const float* __restrict__ vBp,
    const float* __restrict__ kDBp, const float* __restrict__ BtB,
    const int* __restrict__ flag,
    float* __restrict__ kC_g, float* __restrict__ eB_g)
{
    __shared__ float Bsh[256];
    const int t = threadIdx.x;
    Bsh[t] = BtB[t];
    __syncthreads();
    const int dnz = *flag;
    const int n = blockIdx.x * 256 + t;
    const size_t H = (size_t)NROWS * RK;
    float kc[16], vb[16], kdb[16];
    #pragma unroll
    for (int q = 0; q < 4; ++q) {
        const float4 a0 = *(const float4*)(kCp + (size_t)n * RK + q * 4);
        const float4 a1 = *(const float4*)(kCp + H + (size_t)n * RK + q * 4);
        const float4 b0 = *(const float4*)(vBp + (size_t)n * RK + q * 4);
        const float4 b1 = *(const float4*)(vBp + H + (size_t)n * RK + q * 4);
        kc[q*4+0]=a0.x+a1.x; kc[q*4+1]=a0.y+a1.y; kc[q*4+2]=a0.z+a1.z; kc[q*4+3]=a0.w+a1.w;
        vb[q*4+0]=b0.x+b1.x; vb[q*4+1]=b0.y+b1.y; vb[q*4+2]=b0.z+b1.z; vb[q*4+3]=b0.w+b1.w;
        kdb[q*4+0]=0.f; kdb[q*4+1]=0.f; kdb[q*4+2]=0.f; kdb[q*4+3]=0.f;
    }
    if (dnz) {
        #pragma unroll
        for (int q = 0; q < 4; ++q) {
            const float4 c0 = *(const float4*)(kDBp + (size_t)n * RK + q * 4);
            const float4 c1 = *(const float4*)(kDBp + H + (size_t)n * RK + q * 4);
            kdb[q*4+0]=c0.x+c1.x; kdb[q*4+1]=c0.y+c1.y;
            kdb[q*4+2]=c0.z+c1.z; kdb[q*4+3]=c0.w+c1.w;
        }
    }
    float out[16];
    #pragma unroll
    for (int r = 0; r < 16; ++r) {
        float acc = 0.f;
        #pragma unroll
        for (int s = 0; s < 16; ++s) acc += kc[s] * Bsh[s * 16 + r];
        out[r] = vb[r] - kdb[r] - SCALEc * acc;
    }
    #pragma unroll
    for (int q = 0; q < 4; ++q) {
        *(float4*)(kC_g + (size_t)n * RK + q * 4) =
            make_float4(kc[q*4+0], kc[q*4+1], kc[q*4+2], kc[q*4+3]);
        *(float4*)(eB_g + (size_t)n * RK + q * 4) =
            make_float4(out[q*4+0], out[q*4+1], out[q*4+2], out[q*4+3]);
    }
}

// ---------------------------------------------------------------------------
// k_pack: pack kC^T, errB^T into MFMA A-fragments (bf16). 128 blocks x 256.
// ---------------------------------------------------------------------------
__global__ __launch_bounds__(256) void k_pack(
    const float* __restrict__ kC_g, const float* __restrict__ eB_g,
    uint4* __restrict__ kCb, uint4* __restrict__ eBb)
{
    const int idx = blockIdx.x * 256 + threadIdx.x;   // 0..32767
    const int c = idx >> 6, l = idx & 63;
    const int col = l & 15;
    const int nb = c * 32 + (l >> 4) * 8;
    U4S8 ah, bh;
    #pragma unroll
    for (int q = 0; q < 4; ++q) {
        const int n0 = nb + 2 * q;
        ah.u[q] = pk2(kC_g[(size_t)n0 * RK + col], kC_g[(size_t)(n0 + 1) * RK + col]);
        bh.u[q] = pk2(eB_g[(size_t)n0 * RK + col], eB_g[(size_t)(n0 + 1) * RK + col]);
    }
    kCb[idx] = ah.u4;
    eBb[idx] = bh.u4;
}

// ---------------------------------------------------------------------------
// k_T: tall reductions via MFMA, depth-2 prefetch FORCED via sched_barrier
// (compiler was collapsing the buffers: VGPR_Count=36 < one live buffer).
// NT loads for streamed-once k,v; NT stores for write-once partials.
//   Ppart[cgrp] = kC^T@v, Gpart[cgrp] = errB^T@k, Qpart[cgrp] = kC^T@k
//   S2 = kC^T@kC (dgrp==0 only), colsum (atomic).
// grid = 32 dgrp x 64 cgrp = 2048 blocks x 256 thr; wave: 16 d x 8 iters.
// ---------------------------------------------------------------------------
__global__ __launch_bounds__(256) void k_T(
    const float* __restrict__ k, const float* __restrict__ v,
    const uint4* __restrict__ kCb, const uint4* __restrict__ eBb,
    const int* __restrict__ flag,
    float* __restrict__ Ppart, float* __restrict__ Gpart, float* __restrict__ Qpart,
    float* __restrict__ S2, float* __restrict__ colsum)
{
    const int t = threadIdx.x;
    const int lane = t & 63;
    const int w = t >> 6;
    const int dgrp = blockIdx.x & 31;
    const int cgrp = blockIdx.x >> 5;          // 0..63
    const int d = dgrp * 64 + w * 16 + (lane & 15);
    const int rowoff = (lane >> 4) * 8;
    const int c0 = cgrp * 8;
    const int dnz = *flag;
    const int doS = (dgrp == 0);

    floatx4 accP = {0.f,0.f,0.f,0.f}, accG = {0.f,0.f,0.f,0.f};
    floatx4 accQ = {0.f,0.f,0.f,0.f}, accS = {0.f,0.f,0.f,0.f};
    float csl = 0.f;

    uint4 uKA = kCb[(size_t)c0 * 64 + lane];
    uint4 uEA = eBb[(size_t)c0 * 64 + lane];
    uint4 uKB = kCb[(size_t)(c0 + 1) * 64 + lane];
    uint4 uEB = eBb[(size_t)(c0 + 1) * 64 + lane];
    float knA[8], vnA[8], knB[8], vnB[8];
    {
        const float* kpA = k + ((size_t)(c0 * 32 + rowoff)) * DM + d;
        const float* vpA = v + ((size_t)(c0 * 32 + rowoff)) * DM + d;
        const float* kpB = kpA + (size_t)32 * DM;
        const float* vpB = vpA + (size_t)32 * DM;
        #pragma unroll
        for (int e = 0; e < 8; ++e) {
            knA[e] = __builtin_nontemporal_load(kpA + (size_t)e * DM);
            vnA[e] = __builtin_nontemporal_load(vpA + (size_t)e * DM);
            knB[e] = __builtin_nontemporal_load(kpB + (size_t)e * DM);
            vnB[e] = __builtin_nontemporal_load(vpB + (size_t)e * DM);
        }
        __builtin_amdgcn_sched_barrier(0);
    }

    #pragma unroll
    for (int cc = 0; cc < 8; cc += 2) {
        {
            U4S8 uK, uE, kf, vf;
            uK.u4 = uKA; uE.u4 = uEA;
            kf.u[0] = pk2(knA[0], knA[1]); kf.u[1] = pk2(knA[2], knA[3]);
            kf.u[2] = pk2(knA[4], knA[5]); kf.u[3] = pk2(knA[6], knA[7]);
            vf.u[0] = pk2(vnA[0], vnA[1]); vf.u[1] = pk2(vnA[2], vnA[3]);
            vf.u[2] = pk2(vnA[4], vnA[5]); vf.u[3] = pk2(vnA[6], vnA[7]);
            csl += knA[0] + knA[1] + knA[2] + knA[3]
                 + knA[4] + knA[5] + knA[6] + knA[7];

            const int cn = c0 + ((cc + 2 < 8) ? cc + 2 : cc);
            const float* kp = k + ((size_t)(cn * 32 + rowoff)) * DM + d;
            const float* vp = v + ((size_t)(cn * 32 + rowoff)) * DM + d;
            #pragma unroll
            for (int e = 0; e < 8; ++e) {
                knA[e] = __builtin_nontemporal_load(kp + (size_t)e * DM);
                vnA[e] = __builtin_nontemporal_load(vp + (size_t)e * DM);
            }
            uKA = kCb[(size_t)cn * 64 + lane];
            uEA = eBb[(size_t)cn * 64 + lane];
            __builtin_amdgcn_sched_barrier(0);   // pin refill issue here

            accP = __builtin_amdgcn_mfma_f32_16x16x32_bf16(uK.s8, vf.s8, accP, 0, 0, 0);
            accG = __builtin_amdgcn_mfma_f32_16x16x32_bf16(uE.s8, kf.s8, accG, 0, 0, 0);
            if (dnz)
                accQ = __builtin_amdgcn_mfma_f32_16x16x32_bf16(uK.s8, kf.s8, accQ, 0, 0, 0);
            if (doS)
                accS = __builtin_amdgcn_mfma_f32_16x16x32_bf16(uK.s8, uK.s8, accS, 0, 0, 0);
        }
        {
            U4S8 uK, uE, kf, vf;
            uK.u4 = uKB; uE.u4 = uEB;
            kf.u[0] = pk2(knB[0], knB[1]); kf.u[1] = pk2(knB[2], knB[3]);
            kf.u[2] = pk2(knB[4], knB[5]); kf.u[3] = pk2(knB[6], knB[7]);
            vf.u[0] = pk2(vnB[0], vnB[1]); vf.u[1] = pk2(vnB[2], vnB[3]);
            vf.u[2] = pk2(vnB[4], vnB[5]); vf.u[3] = pk2(vnB[6], vnB[7]);
            csl += knB[0] + knB[1] + knB[2] + knB[3]
                 + knB[4] + knB[5] + knB[6] + knB[7];

            const int cn = c0 + ((cc + 3 < 8) ? cc + 3 : cc + 1);
            const float* kp = k + ((size_t)(cn * 32 + rowoff)) * DM + d;
            const float* vp = v + ((size_t)(cn * 32 + rowoff)) * DM + d;
            #pragma unroll
            for (int e = 0; e < 8; ++e) {
                knB[e] = __builtin_nontemporal_load(kp + (size_t)e * DM);
                vnB[e] = __builtin_nontemporal_load(vp + (size_t)e * DM);
            }
            uKB = kCb[(size_t)cn * 64 + lane];
            uEB = eBb[(size_t)cn * 64 + lane];
            __builtin_amdgcn_sched_barrier(0);   // pin refill issue here

            accP = __builtin_amdgcn_mfma_f32_16x16x32_bf16(uK.s8, vf.s8, accP, 0, 0, 0);
            accG = __builtin_amdgcn_mfma_f32_16x16x32_bf16(uE.s8, kf.s8, accG, 0, 0, 0);
            if (dnz)
                accQ = __builtin_amdgcn_mfma_f32_16x16x32_bf16(uK.s8, kf.s8, accQ, 0, 0, 0);
            if (doS)
                accS = __builtin_amdgcn_mfma_f32_16x16x32_bf16(uK.s8, uK.s8, accS, 0, 0, 0);
        }
    }

    const int r0 = (lane >> 4) * 4;
    const size_t o = ((size_t)cgrp * DM + d) * RK + r0;
    __builtin_nontemporal_store(accP, (floatx4*)(Ppart + o));
    __builtin_nontemporal_store(accG, (floatx4*)(Gpart + o));
    if (dnz)
        __builtin_nontemporal_store(accQ, (floatx4*)(Qpart + o));

    if (doS && w == 0) {
        #pragma unroll
        for (int j = 0; j < 4; ++j)
            atomicAdd(S2 + (r0 + j) * RK + (lane & 15), accS[j]);
    }
    csl += __shfl_xor(csl, 16);
    csl += __shfl_xor(csl, 32);
    if ((lane >> 4) == 0) atomicAdd(colsum + d, csl);
}

// ---------------------------------------------------------------------------
// k_ro: ro[n,d] = 0.1*kC[n,:].B[d,:] (+ k*D if flag). Runs LAST (ro region
// doubles as partial-scratch until k_update consumes it). NT stores.
// ---------------------------------------------------------------------------
__global__ __launch_bounds__(256) void k_ro(
    const float* __restrict__ k, const float* __restrict__ B,
    const float* __restrict__ Dd, const float* __restrict__ kC_g,
    const int* __restrict__ flag, float* __restrict__ ro)
{
    __shared__ float kCch[16 * 16];
    const int t = threadIdx.x;
    const int slab = blockIdx.x & 1;
    const int chunk = blockIdx.x >> 1;
    const int d0 = slab * 1024 + t * 4;
    const int row0 = chunk * 16;
    const int dnz = *flag;

    float Breg[4][16], Dreg[4];
    #pragma unroll
    for (int i = 0; i < 4; ++i) {
        #pragma unroll
        for (int q = 0; q < 4; ++q) {
            const float4 b4 = *(const float4*)(B + (size_t)(d0 + i) * RK + q * 4);
            Breg[i][q*4+0] = b4.x; Breg[i][q*4+1] = b4.y;
            Breg[i][q*4+2] = b4.z; Breg[i][q*4+3] = b4.w;
        }
        Dreg[i] = Dd[d0 + i];
    }
    if (t < 64) *(float4*)&kCch[t * 4] = *(const float4*)(kC_g + (size_t)row0 * RK + t * 4);
    __syncthreads();

    float4 k0 = make_float4(0.f,0.f,0.f,0.f), k1 = k0;
    if (dnz) {
        k0 = *(const float4*)(k + (size_t)row0 * DM + d0);
        k1 = *(const float4*)(k + (size_t)(row0 + 1) * DM + d0);
    }

    for (int rr = 0; rr < 16; ++rr) {
        const int n = row0 + rr;
        const float4 kc4 = k0;
        if (dnz) {
            const int np = row0 + ((rr + 2 < 16) ? rr + 2 : 15);
            k0 = k1; k1 = *(const float4*)(k + (size_t)np * DM + d0);
        }
        float kcr[16];
        #pragma unroll
        for (int q = 0; q < 4; ++q) {
            const float4 c4 = *(const float4*)&kCch[rr * 16 + q * 4];
            kcr[q*4+0] = c4.x; kcr[q*4+1] = c4.y; kcr[q*4+2] = c4.z; kcr[q*4+3] = c4.w;
        }
        floatx4 roa;
        const float ka4[4] = {kc4.x, kc4.y, kc4.z, kc4.w};
        #pragma unroll
        for (int i = 0; i < 4; ++i) {
            float s = 0.f;
            #pragma unroll
            for (int r = 0; r < 16; ++r) s += kcr[r] * Breg[i][r];
            roa[i] = SCALEc * s;
            if (dnz) roa[i] += ka4[i] * Dreg[i];
        }
        __builtin_nontemporal_store(roa, (floatx4*)(ro + (size_t)n * DM + d0));
    }
}

// ---------------------------------------------------------------------------
// k_ln: k_mean = colsum/N; h1 = LayerNorm(k_mean)*gamma + beta.
// ---------------------------------------------------------------------------
__global__ __launch_bounds__(256) void k_ln(
    const float* __restrict__ colsum,
    const float* __restrict__ gam, const float* __restrict__ bet,
    float* __restrict__ h1)
{
    __shared__ float red[256];
    __shared__ float mu_sh, var_sh;
    const int t = threadIdx.x;
    float x[8];
    float s = 0.f;
    #pragma unroll
    for (int i = 0; i < 8; ++i) {
        x[i] = colsum[t + 256 * i] * (1.0f / (float)NROWS);
        s += x[i];
    }
    red[t] = s; __syncthreads();
    for (int off = 128; off > 0; off >>= 1) {
        if (t < off) red[t] += red[t + off];
        __syncthreads();
    }
    if (t == 0) mu_sh = red[0] * (1.0f / (float)DM);
    __syncthreads();
    const float mu = mu_sh;
    float s2 = 0.f;
    #pragma unroll
    for (int i = 0; i < 8; ++i) { const float dd = x[i] - mu; s2 += dd * dd; }
    __syncthreads();
    red[t] = s2; __syncthreads();
    for (int off = 128; off > 0; off >>= 1) {
        if (t < off) red[t] += red[t + off];
        __syncthreads();
    }
    if (t == 0) var_sh = red[0] * (1.0f / (float)DM);
    __syncthreads();
    const float rstd = rsqrtf(var_sh + LNEPS);
    #pragma unroll
    for (int i = 0; i < 8; ++i) {
        const int d = t + 256 * i;
        h1[d] = (x[i] - mu) * rstd * gam[d] + bet[d];
    }
}

// ---------------------------------------------------------------------------
// k_gemv: h2[i] = silu(h1 . W1[i,:] + b1[i]). 512 blocks x 256 (wave/row).
// ---------------------------------------------------------------------------
__global__ __launch_bounds__(256) void k_gemv(
    const float* __restrict__ h1, const float* __restrict__ W1,
    const float* __restrict__ b1, float* __restrict__ h2)
{
    const int t = threadIdx.x;
    const int lane = t & 63;
    const int w = t >> 6;
    const int row = blockIdx.x * 4 + w;
    const float* wr = W1 + (size_t)row * DM;
    float s = 0.f;
    #pragma unroll
    for (int j = 0; j < 8; ++j) {
        const float4 a = *(const float4*)(wr + j * 256 + lane * 4);
        const float4 b = *(const float4*)(h1 + j * 256 + lane * 4);
        s += a.x * b.x + a.y * b.y + a.z * b.z + a.w * b.w;
    }
    #pragma unroll
    for (int off = 32; off > 0; off >>= 1) s += __shfl_down(s, off);
    if (lane == 0) {
        const float val = s + b1[row];
        h2[row] = val / (1.0f + expf(-val));
    }
}

// ---------------------------------------------------------------------------
// k_alpha: alpha = sigmoid(h2 . W2 + b2).
// ---------------------------------------------------------------------------
__global__ __launch_bounds__(256) void k_alpha(
    const float* __restrict__ h2, const float* __restrict__ W2,
    const float* __restrict__ b2,
    float* __restrict__ alpha_ws, float* __restrict__ out_alpha)
{
    __shared__ float red[256];
    const int t = threadIdx.x;
    float s = 0.f;
    for (int i = t; i < DM; i += 256) s += h2[i] * W2[i];
    red[t] = s; __syncthreads();
    for (int off = 128; off > 0; off >>= 1) {
        if (t < off) red[t] += red[t + off];
        __syncthreads();
    }
    if (t == 0) {
        const float logit = red[0] + b2[0];
        const float a = 1.0f / (1.0f + expf(-logit));
        alpha_ws[0] = a;
        out_alpha[0] = a;
    }
}

// ---------------------------------------------------------------------------
// k_update: sum 64 partials; G1 = P1 - 0.1*B@S2 - D o Q; grads, momentum,
// B/C update. 128 blocks x 256.
// ---------------------------------------------------------------------------
__global__ __launch_bounds__(256) void k_update(
    const float* __restrict__ B, const float* __restrict__ C,
    const float* __restrict__ Dd,
    const float* __restrict__ S_B, const float* __restrict__ S_C,
    const float* __restrict__ Ppart, const float* __restrict__ Gpart,
    const float* __restrict__ Qpart, const float* __restrict__ S2,
    const float* __restrict__ CtC, const float* __restrict__ BtB,
    const float* __restrict__ alpha_ws, const int* __restrict__ flag,
    float* __restrict__ outB, float* __restrict__ outC,
    float* __restrict__ outSB, float* __restrict__ outSC)
{
    const int idx = blockIdx.x * 256 + threadIdx.x;   // [0, 32768)
    const int d = idx >> 4, r = idx & 15;
    const float alpha = alpha_ws[0];
    const int dnz = *flag;

    float P1v = 0.f, G2v = 0.f, Qv = 0.f;
    const size_t SL = (size_t)DM * RK;
    for (int p = 0; p < 64; ++p) {
        P1v += Ppart[(size_t)p * SL + idx];
        G2v += Gpart[(size_t)p * SL + idx];
    }
    if (dnz)
        for (int p = 0; p < 64; ++p) Qv += Qpart[(size_t)p * SL + idx];

    float Brow[16], Crow[16];
    #pragma unroll
    for (int q = 0; q < 4; ++q) {
        const float4 b4 = *(const float4*)(B + (size_t)d * RK + q * 4);
        const float4 c4 = *(const float4*)(C + (size_t)d * RK + q * 4);
        Brow[q*4+0] = b4.x; Brow[q*4+1] = b4.y; Brow[q*4+2] = b4.z; Brow[q*4+3] = b4.w;
        Crow[q*4+0] = c4.x; Crow[q*4+1] = c4.y; Crow[q*4+2] = c4.z; Crow[q*4+3] = c4.w;
    }
    float bc = 0.f, cb = 0.f, bs2 = 0.f;
    #pragma unroll
    for (int a = 0; a < 16; ++a) {
        bc  += Brow[a] * CtC[a * RK + r];
        cb  += Crow[a] * BtB[a * RK + r];
        bs2 += Brow[a] * S2[a * RK + r];
    }
    const float Ddv = Dd[d];
    const float invN = 1.0f / (float)NROWS;
    const float G1v = P1v - SCALEc * bs2 - Ddv * Qv;
    const float gradB = -G1v * invN + L2c * (SCALEc * bc + Ddv * Crow[r]);
    const float gradC = -G2v * invN + L2c * (SCALEc * cb + Ddv * Brow[r]);
    const float sB = MOMc * S_B[idx] - LRc * gradB;
    const float sC = MOMc * S_C[idx] - LRc * gradC;
    outSB[idx] = sB;
    outSC[idx] = sC;
    outB[idx] = (1.0f - alpha) * B[idx] + sB;
    outC[idx] = (1.0f - alpha) * C[idx] + sC;
}

// ---------------------------------------------------------------------------
extern "C" void kernel_launch(void* const* d_in, const int* in_sizes, int n_in,
                              void* d_out, int out_size, void* d_ws, size_t ws_size,
                              hipStream_t stream)
{
    const float* k   = (const float*)d_in[0];
    const float* v   = (const float*)d_in[1];
    const float* B   = (const float*)d_in[2];
    const float* C   = (const float*)d_in[3];
    const float* Dd  = (const float*)d_in[4];
    const float* S_B = (const float*)d_in[5];
    const float* S_C = (const float*)d_in[6];
    const float* gam = (const float*)d_in[7];
    const float* bet = (const float*)d_in[8];
    const float* W1  = (const float*)d_in[9];
    const float* b1  = (const float*)d_in[10];
    const float* W2  = (const float*)d_in[11];
    const float* b2  = (const float*)d_in[12];

    float* out      = (float*)d_out;
    float* ro       = out;                                  // [N, D] (written LAST)
    float* outB     = out + (size_t)NROWS * DM;
    float* outC     = outB + (size_t)DM * RK;
    float* outSB    = outC + (size_t)DM * RK;
    float* outSC    = outSB + (size_t)DM * RK;
    float* outAlpha = outSC + (size_t)DM * RK;

    // partial slabs live in the (not-yet-written) ro region: 64 x 32768 each
    float* Ppart = ro;                                      // 2,097,152 floats
    float* Gpart = Ppart + (size_t)64 * DM * RK;            // 2,097,152
    float* Qpart = Gpart + (size_t)64 * DM * RK;            // 2,097,152 (24 MB)

    float* ws = (float*)d_ws;
    float* kCp    = ws;                                     // 2 x 262144
    float* vBp    = kCp + (size_t)2 * NROWS * RK;           // 2 x 262144
    float* kDBp   = vBp + (size_t)2 * NROWS * RK;           // 2 x 262144
    float* kC_g   = kDBp + (size_t)2 * NROWS * RK;          // 262144
    float* eB_g   = kC_g + (size_t)NROWS * RK;              // 262144
    float* S2     = eB_g + (size_t)NROWS * RK;              // 256 -- zero start
    float* CtC    = S2 + 256;                               // 256
    float* BtB    = CtC + 256;                              // 256
    float* colsum = BtB + 256;                              // 2048 -- zero end
    float* h1     = colsum + DM;                            // 2048
    float* h2     = h1 + DM;                                // 2048
    uint4* Cpk    = (uint4*)(h2 + DM);                      // 4096 uint4
    uint4* Bpk    = Cpk + 4096;
    uint4* DBpk   = Bpk + 4096;
    uint4* kCb    = DBpk + 4096;                            // 32768 uint4
    uint4* eBb    = kCb + 32768;                            // 32768 uint4
    float* alphaW = (float*)(eBb + 32768);
    int*   flag   = (int*)(alphaW + 1);

    // zero only S2/CtC/BtB/colsum: 2816 floats
    hipMemsetAsync(S2, 0, (size_t)2816 * sizeof(float), stream);

    hipLaunchKernelGGL(k_prep, dim3(33), dim3(256), 0, stream,
                       B, C, Dd, BtB, CtC, Cpk, Bpk, DBpk, flag);
    hipLaunchKernelGGL(k_A, dim3(2048), dim3(256), 0, stream,
                       k, v, Cpk, Bpk, DBpk, flag, kCp, vBp, kDBp);
    hipLaunchKernelGGL(k_mid, dim3(64), dim3(256), 0, stream,
                       kCp, vBp, kDBp, BtB, flag, kC_g, eB_g);
    hipLaunchKernelGGL(k_pack, dim3(128), dim3(256), 0, stream,
                       kC_g, eB_g, kCb, eBb);
    hipLaunchKernelGGL(k_T, dim3(2048), dim3(256), 0, stream,
                       k, v, kCb, eBb, flag, Ppart, Gpart, Qpart, S2, colsum);
    hipLaunchKernelGGL(k_ln, dim3(1), dim3(256), 0, stream, colsum, gam, bet, h1);
    hipLaunchKernelGGL(k_gemv, dim3(512), dim3(256), 0, stream, h1, W1, b1, h2);
    hipLaunchKernelGGL(k_alpha, dim3(1), dim3(256), 0, stream, h2, W2, b2, alphaW, outAlpha);
    hipLaunchKernelGGL(k_update, dim3(128), dim3(256), 0, stream,
                       B, C, Dd, S_B, S_C, Ppart, Gpart, Qpart, S2, CtC, BtB,
                       alphaW, flag, outB, outC, outSB, outSC);
    hipLaunchKernelGGL(k_ro, dim3(2048), dim3(256), 0, stream,
                       k, B, Dd, kC_g, flag, ro);
}

// Round 12
// 182.142 us; speedup vs baseline: 1.1444x; 1.1444x over previous
//
#include <hip/hip_runtime.h>
#include <hip/hip_bf16.h>
#include <math.h>

#define NROWS 16384
#define DM    2048
#define RK    16
#define LRc    1e-3f
#define L2c    1e-4f
#define MOMc   0.9f
#define SCALEc 0.1f
#define LNEPS  1e-5f

typedef __attribute__((ext_vector_type(8))) short short8;
typedef __attribute__((ext_vector_type(4))) float floatx4;

union U4S8 { uint4 u4; short8 s8; unsigned u[4]; };

__device__ inline unsigned pk2(float lo, float hi) {
    union { __hip_bfloat162 h; unsigned u; } cv;
    cv.h = __float22bfloat162_rn(make_float2(lo, hi));
    return cv.u;
}

// direct global->LDS DMA, 16B per lane (default cache policy: keep L3 warm)
__device__ __forceinline__ void gld16(const float* g, float* l) {
    __builtin_amdgcn_global_load_lds(
        (const __attribute__((address_space(1))) unsigned*)g,
        (__attribute__((address_space(3))) unsigned*)l,
        16, 0, 0);
}

// ---------------------------------------------------------------------------
// k_prep: blocks 0-15: BtB/CtC (atomic). blocks 16-31: pack B,C,D∘B into
// MFMA fragment layout. block 32: D!=0 flag.
// ---------------------------------------------------------------------------
__global__ __launch_bounds__(256) void k_prep(
    const float* __restrict__ B, const float* __restrict__ C,
    const float* __restrict__ Dd,
    float* __restrict__ BtB, float* __restrict__ CtC,
    uint4* __restrict__ Cpk, uint4* __restrict__ Bpk, uint4* __restrict__ DBpk,
    int* __restrict__ flag)
{
    const int bid = blockIdx.x, t = threadIdx.x;
    if (bid < 16) {
        const int a = t >> 4, b = t & 15;
        const int dBeg = bid * 128;
        float sc = 0.f, sb = 0.f;
        for (int d = dBeg; d < dBeg + 128; ++d) {
            sc += C[d * RK + a] * C[d * RK + b];
            sb += B[d * RK + a] * B[d * RK + b];
        }
        atomicAdd(CtC + a * RK + b, sc);
        atomicAdd(BtB + a * RK + b, sb);
    } else if (bid < 32) {
        const int idx = (bid - 16) * 256 + t;      // 4096 = 64 chunks x 64 lanes
        const int c = idx >> 6, l = idx & 63;
        const int dbase = c * 32 + (l >> 4) * 8;
        const int col = l & 15;
        U4S8 uc, ub, ud;
        #pragma unroll
        for (int q = 0; q < 4; ++q) {
            const int d0 = dbase + 2 * q, d1 = d0 + 1;
            uc.u[q] = pk2(C[d0 * RK + col], C[d1 * RK + col]);
            ub.u[q] = pk2(B[d0 * RK + col], B[d1 * RK + col]);
            ud.u[q] = pk2(Dd[d0] * B[d0 * RK + col], Dd[d1] * B[d1 * RK + col]);
        }
        Cpk[idx] = uc.u4; Bpk[idx] = ub.u4; DBpk[idx] = ud.u4;
    } else {
        __shared__ int sh;
        if (t == 0) sh = 0;
        __syncthreads();
        int any = 0;
        for (int i = t; i < DM; i += 256) any |= (Dd[i] != 0.f) ? 1 : 0;
        if (any) sh = 1;
        __syncthreads();
        if (t == 0) *flag = sh;
    }
}

// ---------------------------------------------------------------------------
// k_A: BARRIER-FREE LDS-staged MFMA row-reductions. Each wave owns a PRIVATE
// double-buffered tile [2 bufs][k,v][16 rows x 32 d] (8 KB/wave, 32 KB/block)
// staged with its own 4 global_load_lds per chunk -- no cross-wave sharing,
// NO __syncthreads in the hot loop (waves drain independently like k_T,
// which sustains 6.4 TB/s; the per-chunk block barrier was the convoy).
// XOR swizzle (piece ^ row&7) on source + read keeps ds_read 2-way.
// Block = 16 rows x 2048 d, 4 waves x 16 chunks of 32 d. 1024 blocks.
//   kC = k@C, vB = v@B, kDB = (k o D)@B (skipped when D==0).
// ---------------------------------------------------------------------------
__global__ __launch_bounds__(256) void k_A(
    const float* __restrict__ k, const float* __restrict__ v,
    const uint4* __restrict__ Cpk, const uint4* __restrict__ Bpk,
    const uint4* __restrict__ DBpk, const int* __restrict__ flag,
    float* __restrict__ kC_g, float* __restrict__ vB_g, float* __restrict__ eB_g)
{
    __shared__ float kt[4][2][2][512];   // [wave][buf][k/v][16 rows x 32 f] 32 KB
    const int t = threadIdx.x;
    const int lane = t & 63;
    const int w = t >> 6;
    const int R0 = blockIdx.x * 16;
    const int m = lane & 15;
    const int g = lane >> 4;
    const int dnz = *flag;

    // staging lane geometry: srow 0..7, piece p 0..7; swizzled source piece
    const int srow = lane >> 3;
    const int colp = ((lane & 7) ^ (srow & 7)) << 2;   // swizzled piece * 4

    floatx4 a0 = {0.f,0.f,0.f,0.f}, a1 = {0.f,0.f,0.f,0.f}, a2 = {0.f,0.f,0.f,0.f};

    // per-wave chunk j -> global 32-d chunk cc = w*16 + j, d0 = cc*32
    #define STAGE_W(j_, buf_) {                                               \
        const int d0_ = (w * 16 + (j_)) << 5;                                 \
        gld16(k + (size_t)(R0 + srow) * DM + d0_ + colp,                      \
              &kt[w][buf_][0][0]);                                            \
        gld16(k + (size_t)(R0 + 8 + srow) * DM + d0_ + colp,                  \
              &kt[w][buf_][0][256]);                                          \
        gld16(v + (size_t)(R0 + srow) * DM + d0_ + colp,                      \
              &kt[w][buf_][1][0]);                                            \
        gld16(v + (size_t)(R0 + 8 + srow) * DM + d0_ + colp,                  \
              &kt[w][buf_][1][256]);                                          \
    }

    STAGE_W(0, 0);

    // ds_read offsets (floats): row = m, pieces q0 = 2g, q0+1, swizzled
    const int q0 = 2 * g;
    const int off1 = m * 32 + ((q0 ^ (m & 7)) << 2);
    const int off2 = m * 32 + (((q0 + 1) ^ (m & 7)) << 2);

    for (int j = 0; j < 16; ++j) {
        const int buf = j & 1;

        // frag loads first (older than next-chunk staging in vmcnt order)
        const int cc = w * 16 + j;
        uint4 cf = Cpk[cc * 64 + lane];
        uint4 bf = Bpk[cc * 64 + lane];
        uint4 df = make_uint4(0u,0u,0u,0u);
        if (dnz) df = DBpk[cc * 64 + lane];

        if (j + 1 < 16) STAGE_W(j + 1, buf ^ 1);

        const float4 kx = *(const float4*)&kt[w][buf][0][off1];
        const float4 ky = *(const float4*)&kt[w][buf][0][off2];
        const float4 vx = *(const float4*)&kt[w][buf][1][off1];
        const float4 vy = *(const float4*)&kt[w][buf][1][off2];

        U4S8 kf, vf, cu, bu, du;
        kf.u[0] = pk2(kx.x, kx.y); kf.u[1] = pk2(kx.z, kx.w);
        kf.u[2] = pk2(ky.x, ky.y); kf.u[3] = pk2(ky.z, ky.w);
        vf.u[0] = pk2(vx.x, vx.y); vf.u[1] = pk2(vx.z, vx.w);
        vf.u[2] = pk2(vy.x, vy.y); vf.u[3] = pk2(vy.z, vy.w);
        cu.u4 = cf; bu.u4 = bf; du.u4 = df;

        a0 = __builtin_amdgcn_mfma_f32_16x16x32_bf16(kf.s8, cu.s8, a0, 0, 0, 0);
        a1 = __builtin_amdgcn_mfma_f32_16x16x32_bf16(vf.s8, bu.s8, a1, 0, 0, 0);
        if (dnz)
            a2 = __builtin_amdgcn_mfma_f32_16x16x32_bf16(kf.s8, du.s8, a2, 0, 0, 0);
    }
    #undef STAGE_W

    // cross-wave K-reduce (the ONLY barriers): reuse kt as floatx4[3][4][64]
    __syncthreads();
    floatx4* red = (floatx4*)&kt[0][0][0][0];
    red[(0 * 4 + w) * 64 + lane] = a0;
    red[(1 * 4 + w) * 64 + lane] = a1;
    red[(2 * 4 + w) * 64 + lane] = a2;
    __syncthreads();
    if (w == 0) {
        const floatx4 s0 = red[0*256+0*64+lane] + red[0*256+1*64+lane]
                         + red[0*256+2*64+lane] + red[0*256+3*64+lane];
        const floatx4 s1 = red[1*256+0*64+lane] + red[1*256+1*64+lane]
                         + red[1*256+2*64+lane] + red[1*256+3*64+lane];
        const floatx4 s2 = red[2*256+0*64+lane] + red[2*256+1*64+lane]
                         + red[2*256+2*64+lane] + red[2*256+3*64+lane];
        #pragma unroll
        for (int j = 0; j < 4; ++j) {
            const size_t o = (size_t)(R0 + g * 4 + j) * RK + m;
            kC_g[o] = s0[j];
            vB_g[o] = s1[j];
            if (dnz) eB_g[o] = s2[j];   // holds kDB until k_mid rewrites
        }
    }
}

// ---------------------------------------------------------------------------
// k_mid: errB = vB - kDB - 0.1*kC@BtB (in-place over eB_g). 64 blocks x 256.
// ---------------------------------------------------------------------------
__global__ __launch_bounds__(256) void k_mid(
    const float* __restrict__ kC_g, const float* __restrict__ vB_g,
    float* __restrict__ eB_g, const float* __restrict__ BtB,
    const int* __restrict__ flag)
{
    __shared__ float Bsh[256];
    const int t = threadIdx.x;
    Bsh[t] = BtB[t];
    __syncthreads();
    const int dnz = *flag;
    const int n = blockIdx.x * 256 + t;
    float kc[16], vb[16], kdb[16];
    #pragma unroll
    for (int q = 0; q < 4; ++q) {
        const float4 a = *(const float4*)(kC_g + (size_t)n * RK + q * 4);
        const float4 b = *(const float4*)(vB_g + (size_t)n * RK + q * 4);
        kc[q*4+0]=a.x; kc[q*4+1]=a.y; kc[q*4+2]=a.z; kc[q*4+3]=a.w;
        vb[q*4+0]=b.x; vb[q*4+1]=b.y; vb[q*4+2]=b.z; vb[q*4+3]=b.w;
        kdb[q*4+0]=0.f; kdb[q*4+1]=0.f; kdb[q*4+2]=0.f; kdb[q*4+3]=0.f;
    }
    if (dnz) {
        #pragma unroll
        for (int q = 0; q < 4; ++q) {
            const float4 c = *(const float4*)(eB_g + (size_t)n * RK + q * 4);
            kdb[q*4+0]=c.x; kdb[q*4+1]=c.y; kdb[q*4+2]=c.z; kdb[q*4+3]=c.w;
        }
    }
    float out[16];
    #pragma unroll
    for (int r = 0; r < 16; ++r) {
        float acc = 0.f;
        #pragma unroll
        for (int s = 0; s < 16; ++s) acc += kc[s] * Bsh[s * 16 + r];
        out[r] = vb[r] - kdb[r] - SCALEc * acc;
    }
    #pragma unroll
    for (int q = 0; q < 4; ++q)
        *(float4*)(eB_g + (size_t)n * RK + q * 4) =
            make_float4(out[q*4+0], out[q*4+1], out[q*4+2], out[q*4+3]);
}

// ---------------------------------------------------------------------------
// k_pack: pack kC^T, errB^T into MFMA A-fragments (bf16). 128 blocks x 256.
// ---------------------------------------------------------------------------
__global__ __launch_bounds__(256) void k_pack(
    const float* __restrict__ kC_g, const float* __restrict__ eB_g,
    uint4* __restrict__ kCb, uint4* __restrict__ eBb)
{
    const int idx = blockIdx.x * 256 + threadIdx.x;   // 0..32767
    const int c = idx >> 6, l = idx & 63;
    const int col = l & 15;
    const int nb = c * 32 + (l >> 4) * 8;
    U4S8 ah, bh;
    #pragma unroll
    for (int q = 0; q < 4; ++q) {
        const int n0 = nb + 2 * q;
        ah.u[q] = pk2(kC_g[(size_t)n0 * RK + col], kC_g[(size_t)(n0 + 1) * RK + col]);
        bh.u[q] = pk2(eB_g[(size_t)n0 * RK + col], eB_g[(size_t)(n0 + 1) * RK + col]);
    }
    kCb[idx] = ah.u4;
    eBb[idx] = bh.u4;
}

// ---------------------------------------------------------------------------
// k_T: tall reductions via MFMA, depth-2 prefetch pinned via sched_barrier.
// Plain (cacheable) loads so k/v stay L3-resident from k_A; NT stores for
// write-once partials.
//   Ppart[cgrp] = kC^T@v, Gpart[cgrp] = errB^T@k, Qpart[cgrp] = kC^T@k
//   S2 = kC^T@kC (dgrp==0 only), colsum (atomic).
// grid = 32 dgrp x 64 cgrp = 2048 blocks x 256 thr; wave: 16 d x 8 iters.
// ---------------------------------------------------------------------------
__global__ __launch_bounds__(256) void k_T(
    const float* __restrict__ k, const float* __restrict__ v,
    const uint4* __restrict__ kCb, const uint4* __restrict__ eBb,
    const int* __restrict__ flag,
    float* __restrict__ Ppart, float* __restrict__ Gpart, float* __restrict__ Qpart,
    float* __restrict__ S2, float* __restrict__ colsum)
{
    const int t = threadIdx.x;
    const int lane = t & 63;
    const int w = t >> 6;
    const int dgrp = blockIdx.x & 31;
    const int cgrp = blockIdx.x >> 5;          // 0..63
    const int d = dgrp * 64 + w * 16 + (lane & 15);
    const int rowoff = (lane >> 4) * 8;
    const int c0 = cgrp * 8;
    const int dnz = *flag;
    const int doS = (dgrp == 0);

    floatx4 accP = {0.f,0.f,0.f,0.f}, accG = {0.f,0.f,0.f,0.f};
    floatx4 accQ = {0.f,0.f,0.f,0.f}, accS = {0.f,0.f,0.f,0.f};
    float csl = 0.f;

    uint4 uKA = kCb[(size_t)c0 * 64 + lane];
    uint4 uEA = eBb[(size_t)c0 * 64 + lane];
    uint4 uKB = kCb[(size_t)(c0 + 1) * 64 + lane];
    uint4 uEB = eBb[(size_t)(c0 + 1) * 64 + lane];
    float knA[8], vnA[8], knB[8], vnB[8];
    {
        const float* kpA = k + ((size_t)(c0 * 32 + rowoff)) * DM + d;
        const float* vpA = v + ((size_t)(c0 * 32 + rowoff)) * DM + d;
        const float* kpB = kpA + (size_t)32 * DM;
        const float* vpB = vpA + (size_t)32 * DM;
        #pragma unroll
        for (int e = 0; e < 8; ++e) {
            knA[e] = kpA[(size_t)e * DM];
            vnA[e] = vpA[(size_t)e * DM];
            knB[e] = kpB[(size_t)e * DM];
            vnB[e] = vpB[(size_t)e * DM];
        }
        __builtin_amdgcn_sched_barrier(0);
    }

    #pragma unroll
    for (int cc = 0; cc < 8; cc += 2) {
        {
            U4S8 uK, uE, kf, vf;
            uK.u4 = uKA; uE.u4 = uEA;
            kf.u[0] = pk2(knA[0], knA[1]); kf.u[1] = pk2(knA[2], knA[3]);
            kf.u[2] = pk2(knA[4], knA[5]); kf.u[3] = pk2(knA[6], knA[7]);
            vf.u[0] = pk2(vnA[0], vnA[1]); vf.u[1] = pk2(vnA[2], vnA[3]);
            vf.u[2] = pk2(vnA[4], vnA[5]); vf.u[3] = pk2(vnA[6], vnA[7]);
            csl += knA[0] + knA[1] + knA[2] + knA[3]
                 + knA[4] + knA[5] + knA[6] + knA[7];

            const int cn = c0 + ((cc + 2 < 8) ? cc + 2 : cc);
            const float* kp = k + ((size_t)(cn * 32 + rowoff)) * DM + d;
            const float* vp = v + ((size_t)(cn * 32 + rowoff)) * DM + d;
            #pragma unroll
            for (int e = 0; e < 8; ++e) {
                knA[e] = kp[(size_t)e * DM];
                vnA[e] = vp[(size_t)e * DM];
            }
            uKA = kCb[(size_t)cn * 64 + lane];
            uEA = eBb[(size_t)cn * 64 + lane];
            __builtin_amdgcn_sched_barrier(0);   // pin refill issue here

            accP = __builtin_amdgcn_mfma_f32_16x16x32_bf16(uK.s8, vf.s8, accP, 0, 0, 0);
            accG = __builtin_amdgcn_mfma_f32_16x16x32_bf16(uE.s8, kf.s8, accG, 0, 0, 0);
            if (dnz)
                accQ = __builtin_amdgcn_mfma_f32_16x16x32_bf16(uK.s8, kf.s8, accQ, 0, 0, 0);
            if (doS)
                accS = __builtin_amdgcn_mfma_f32_16x16x32_bf16(uK.s8, uK.s8, accS, 0, 0, 0);
        }
        {
            U4S8 uK, uE, kf, vf;
            uK.u4 = uKB; uE.u4 = uEB;
            kf.u[0] = pk2(knB[0], knB[1]); kf.u[1] = pk2(knB[2], knB[3]);
            kf.u[2] = pk2(knB[4], knB[5]); kf.u[3] = pk2(knB[6], knB[7]);
            vf.u[0] = pk2(vnB[0], vnB[1]); vf.u[1] = pk2(vnB[2], vnB[3]);
            vf.u[2] = pk2(vnB[4], vnB[5]); vf.u[3] = pk2(vnB[6], vnB[7]);
            csl += knB[0] + knB[1] + knB[2] + knB[3]
                 + knB[4] + knB[5] + knB[6] + knB[7];

            const int cn = c0 + ((cc + 3 < 8) ? cc + 3 : cc + 1);
            const float* kp = k + ((size_t)(cn * 32 + rowoff)) * DM + d;
            const float* vp = v + ((size_t)(cn * 32 + rowoff)) * DM + d;
            #pragma unroll
            for (int e = 0; e < 8; ++e) {
                knB[e] = kp[(size_t)e * DM];
                vnB[e] = vp[(size_t)e * DM];
            }
            uKB = kCb[(size_t)cn * 64 + lane];
            uEB = eBb[(size_t)cn * 64 + lane];
            __builtin_amdgcn_sched_barrier(0);   // pin refill issue here

            accP = __builtin_amdgcn_mfma_f32_16x16x32_bf16(uK.s8, vf.s8, accP, 0, 0, 0);
            accG = __builtin_amdgcn_mfma_f32_16x16x32_bf16(uE.s8, kf.s8, accG, 0, 0, 0);
            if (dnz)
                accQ = __builtin_amdgcn_mfma_f32_16x16x32_bf16(uK.s8, kf.s8, accQ, 0, 0, 0);
            if (doS)
                accS = __builtin_amdgcn_mfma_f32_16x16x32_bf16(uK.s8, uK.s8, accS, 0, 0, 0);
        }
    }

    const int r0 = (lane >> 4) * 4;
    const size_t o = ((size_t)cgrp * DM + d) * RK + r0;
    __builtin_nontemporal_store(accP, (floatx4*)(Ppart + o));
    __builtin_nontemporal_store(accG, (floatx4*)(Gpart + o));
    if (dnz)
        __builtin_nontemporal_store(accQ, (floatx4*)(Qpart + o));

    if (doS && w == 0) {
        #pragma unroll
        for (int j = 0; j < 4; ++j)
            atomicAdd(S2 + (r0 + j) * RK + (lane & 15), accS[j]);
    }
    csl += __shfl_xor(csl, 16);
    csl += __shfl_xor(csl, 32);
    if ((lane >> 4) == 0) atomicAdd(colsum + d, csl);
}

// ---------------------------------------------------------------------------
// k_ro: ro[n,d] = 0.1*kC[n,:].B[d,:] (+ k*D if flag). Runs LAST (ro region
// doubles as partial-scratch until k_update consumes it). NT stores.
// ---------------------------------------------------------------------------
__global__ __launch_bounds__(256) void k_ro(
    const float* __restrict__ k, const float* __restrict__ B,
    const float* __restrict__ Dd, const float* __restrict__ kC_g,
    const int* __restrict__ flag, float* __restrict__ ro)
{
    __shared__ float kCch[16 * 16];
    const int t = threadIdx.x;
    const int slab = blockIdx.x & 1;
    const int chunk = blockIdx.x >> 1;
    const int d0 = slab * 1024 + t * 4;
    const int row0 = chunk * 16;
    const int dnz = *flag;

    float Breg[4][16], Dreg[4];
    #pragma unroll
    for (int i = 0; i < 4; ++i) {
        #pragma unroll
        for (int q = 0; q < 4; ++q) {
            const float4 b4 = *(const float4*)(B + (size_t)(d0 + i) * RK + q * 4);
            Breg[i][q*4+0] = b4.x; Breg[i][q*4+1] = b4.y;
            Breg[i][q*4+2] = b4.z; Breg[i][q*4+3] = b4.w;
        }
        Dreg[i] = Dd[d0 + i];
    }
    if (t < 64) *(float4*)&kCch[t * 4] = *(const float4*)(kC_g + (size_t)row0 * RK + t * 4);
    __syncthreads();

    float4 k0 = make_float4(0.f,0.f,0.f,0.f), k1 = k0;
    if (dnz) {
        k0 = *(const float4*)(k + (size_t)row0 * DM + d0);
        k1 = *(const float4*)(k + (size_t)(row0 + 1) * DM + d0);
    }

    for (int rr = 0; rr < 16; ++rr) {
        const int n = row0 + rr;
        const float4 kc4 = k0;
        if (dnz) {
            const int np = row0 + ((rr + 2 < 16) ? rr + 2 : 15);
            k0 = k1; k1 = *(const float4*)(k + (size_t)np * DM + d0);
        }
        float kcr[16];
        #pragma unroll
        for (int q = 0; q < 4; ++q) {
            const float4 c4 = *(const float4*)&kCch[rr * 16 + q * 4];
            kcr[q*4+0] = c4.x; kcr[q*4+1] = c4.y; kcr[q*4+2] = c4.z; kcr[q*4+3] = c4.w;
        }
        floatx4 roa;
        const float ka4[4] = {kc4.x, kc4.y, kc4.z, kc4.w};
        #pragma unroll
        for (int i = 0; i < 4; ++i) {
            float s = 0.f;
            #pragma unroll
            for (int r = 0; r < 16; ++r) s += kcr[r] * Breg[i][r];
            roa[i] = SCALEc * s;
            if (dnz) roa[i] += ka4[i] * Dreg[i];
        }
        __builtin_nontemporal_store(roa, (floatx4*)(ro + (size_t)n * DM + d0));
    }
}

// ---------------------------------------------------------------------------
// k_ln: k_mean = colsum/N; h1 = LayerNorm(k_mean)*gamma + beta.
// ---------------------------------------------------------------------------
__global__ __launch_bounds__(256) void k_ln(
    const float* __restrict__ colsum,
    const float* __restrict__ gam, const float* __restrict__ bet,
    float* __restrict__ h1)
{
    __shared__ float red[256];
    __shared__ float mu_sh, var_sh;
    const int t = threadIdx.x;
    float x[8];
    float s = 0.f;
    #pragma unroll
    for (int i = 0; i < 8; ++i) {
        x[i] = colsum[t + 256 * i] * (1.0f / (float)NROWS);
        s += x[i];
    }
    red[t] = s; __syncthreads();
    for (int off = 128; off > 0; off >>= 1) {
        if (t < off) red[t] += red[t + off];
        __syncthreads();
    }
    if (t == 0) mu_sh = red[0] * (1.0f / (float)DM);
    __syncthreads();
    const float mu = mu_sh;
    float s2 = 0.f;
    #pragma unroll
    for (int i = 0; i < 8; ++i) { const float dd = x[i] - mu; s2 += dd * dd; }
    __syncthreads();
    red[t] = s2; __syncthreads();
    for (int off = 128; off > 0; off >>= 1) {
        if (t < off) red[t] += red[t + off];
        __syncthreads();
    }
    if (t == 0) var_sh = red[0] * (1.0f / (float)DM);
    __syncthreads();
    const float rstd = rsqrtf(var_sh + LNEPS);
    #pragma unroll
    for (int i = 0; i < 8; ++i) {
        const int d = t + 256 * i;
        h1[d] = (x[i] - mu) * rstd * gam[d] + bet[d];
    }
}

// ---------------------------------------------------------------------------
// k_gemv: h2[i] = silu(h1 . W1[i,:] + b1[i]). 512 blocks x 256 (wave/row).
// ---------------------------------------------------------------------------
__global__ __launch_bounds__(256) void k_gemv(
    const float* __restrict__ h1, const float* __restrict__ W1,
    const float* __restrict__ b1, float* __restrict__ h2)
{
    const int t = threadIdx.x;
    const int lane = t & 63;
    const int w = t >> 6;
    const int row = blockIdx.x * 4 + w;
    const float* wr = W1 + (size_t)row * DM;
    float s = 0.f;
    #pragma unroll
    for (int j = 0; j < 8; ++j) {
        const float4 a = *(const float4*)(wr + j * 256 + lane * 4);
        const float4 b = *(const float4*)(h1 + j * 256 + lane * 4);
        s += a.x * b.x + a.y * b.y + a.z * b.z + a.w * b.w;
    }
    #pragma unroll
    for (int off = 32; off > 0; off >>= 1) s += __shfl_down(s, off);
    if (lane == 0) {
        const float val = s + b1[row];
        h2[row] = val / (1.0f + expf(-val));
    }
}

// ---------------------------------------------------------------------------
// k_alpha: alpha = sigmoid(h2 . W2 + b2).
// ---------------------------------------------------------------------------
__global__ __launch_bounds__(256) void k_alpha(
    const float* __restrict__ h2, const float* __restrict__ W2,
    const float* __restrict__ b2,
    float* __restrict__ alpha_ws, float* __restrict__ out_alpha)
{
    __shared__ float red[256];
    const int t = threadIdx.x;
    float s = 0.f;
    for (int i = t; i < DM; i += 256) s += h2[i] * W2[i];
    red[t] = s; __syncthreads();
    for (int off = 128; off > 0; off >>= 1) {
        if (t < off) red[t] += red[t + off];
        __syncthreads();
    }
    if (t == 0) {
        const float logit = red[0] + b2[0];
        const float a = 1.0f / (1.0f + expf(-logit));
        alpha_ws[0] = a;
        out_alpha[0] = a;
    }
}

// ---------------------------------------------------------------------------
// k_update: sum 64 partials; G1 = P1 - 0.1*B@S2 - D o Q; grads, momentum,
// B/C update. 128 blocks x 256.
// ---------------------------------------------------------------------------
__global__ __launch_bounds__(256) void k_update(
    const float* __restrict__ B, const float* __restrict__ C,
    const float* __restrict__ Dd,
    const float* __restrict__ S_B, const float* __restrict__ S_C,
    const float* __restrict__ Ppart, const float* __restrict__ Gpart,
    const float* __restrict__ Qpart, const float* __restrict__ S2,
    const float* __restrict__ CtC, const float* __restrict__ BtB,
    const float* __restrict__ alpha_ws, const int* __restrict__ flag,
    float* __restrict__ outB, float* __restrict__ outC,
    float* __restrict__ outSB, float* __restrict__ outSC)
{
    const int idx = blockIdx.x * 256 + threadIdx.x;   // [0, 32768)
    const int d = idx >> 4, r = idx & 15;
    const float alpha = alpha_ws[0];
    const int dnz = *flag;

    float P1v = 0.f, G2v = 0.f, Qv = 0.f;
    const size_t SL = (size_t)DM * RK;
    for (int p = 0; p < 64; ++p) {
        P1v += Ppart[(size_t)p * SL + idx];
        G2v += Gpart[(size_t)p * SL + idx];
    }
    if (dnz)
        for (int p = 0; p < 64; ++p) Qv += Qpart[(size_t)p * SL + idx];

    float Brow[16], Crow[16];
    #pragma unroll
    for (int q = 0; q < 4; ++q) {
        const float4 b4 = *(const float4*)(B + (size_t)d * RK + q * 4);
        const float4 c4 = *(const float4*)(C + (size_t)d * RK + q * 4);
        Brow[q*4+0] = b4.x; Brow[q*4+1] = b4.y; Brow[q*4+2] = b4.z; Brow[q*4+3] = b4.w;
        Crow[q*4+0] = c4.x; Crow[q*4+1] = c4.y; Crow[q*4+2] = c4.z; Crow[q*4+3] = c4.w;
    }
    float bc = 0.f, cb = 0.f, bs2 = 0.f;
    #pragma unroll
    for (int a = 0; a < 16; ++a) {
        bc  += Brow[a] * CtC[a * RK + r];
        cb  += Crow[a] * BtB[a * RK + r];
        bs2 += Brow[a] * S2[a * RK + r];
    }
    const float Ddv = Dd[d];
    const float invN = 1.0f / (float)NROWS;
    const float G1v = P1v - SCALEc * bs2 - Ddv * Qv;
    const float gradB = -G1v * invN + L2c * (SCALEc * bc + Ddv * Crow[r]);
    const float gradC = -G2v * invN + L2c * (SCALEc * cb + Ddv * Brow[r]);
    const float sB = MOMc * S_B[idx] - LRc * gradB;
    const float sC = MOMc * S_C[idx] - LRc * gradC;
    outSB[idx] = sB;
    outSC[idx] = sC;
    outB[idx] = (1.0f - alpha) * B[idx] + sB;
    outC[idx] = (1.0f - alpha) * C[idx] + sC;
}

// ---------------------------------------------------------------------------
extern "C" void kernel_launch(void* const* d_in, const int* in_sizes, int n_in,
                              void* d_out, int out_size, void* d_ws, size_t ws_size,
                              hipStream_t stream)
{
    const float* k   = (const float*)d_in[0];
    const float* v   = (const float*)d_in[1];
    const float* B   = (const float*)d_in[2];
    const float* C   = (const float*)d_in[3];
    const float* Dd  = (const float*)d_in[4];
    const float* S_B = (const float*)d_in[5];
    const float* S_C = (const float*)d_in[6];
    const float* gam = (const float*)d_in[7];
    const float* bet = (const float*)d_in[8];
    const float* W1  = (const float*)d_in[9];
    const float* b1  = (const float*)d_in[10];
    const float* W2  = (const float*)d_in[11];
    const float* b2  = (const float*)d_in[12];

    float* out      = (float*)d_out;
    float* ro       = out;                                  // [N, D] (written LAST)
    float* outB     = out + (size_t)NROWS * DM;
    float* outC     = outB + (size_t)DM * RK;
    float* outSB    = outC + (size_t)DM * RK;
    float* outSC    = outSB + (size_t)DM * RK;
    float* outAlpha = outSC + (size_t)DM * RK;

    // partial slabs live in the (not-yet-written) ro region: 64 x 32768 each
    float* Ppart = ro;                                      // 2,097,152 floats
    float* Gpart = Ppart + (size_t)64 * DM * RK;            // 2,097,152
    float* Qpart = Gpart + (size_t)64 * DM * RK;            // 2,097,152 (24 MB)

    float* ws = (float*)d_ws;
    float* kC_g   = ws;                                     // 262144
    float* vB_g   = kC_g + (size_t)NROWS * RK;              // 262144
    float* eB_g   = vB_g + (size_t)NROWS * RK;              // 262144 (kDB -> errB)
    float* S2     = eB_g + (size_t)NROWS * RK;              // 256 -- zero start
    float* CtC    = S2 + 256;                               // 256
    float* BtB    = CtC + 256;                              // 256
    float* colsum = BtB + 256;                              // 2048 -- zero end
    float* h1     = colsum + DM;                            // 2048
    float* h2     = h1 + DM;                                // 2048
    uint4* Cpk    = (uint4*)(h2 + DM);                      // 4096 uint4
    uint4* Bpk    = Cpk + 4096;
    uint4* DBpk   = Bpk + 4096;
    uint4* kCb    = DBpk + 4096;                            // 32768 uint4
    uint4* eBb    = kCb + 32768;                            // 32768 uint4
    float* alphaW = (float*)(eBb + 32768);
    int*   flag   = (int*)(alphaW + 1);

    // zero only S2/CtC/BtB/colsum: 2816 floats
    hipMemsetAsync(S2, 0, (size_t)2816 * sizeof(float), stream);

    hipLaunchKernelGGL(k_prep, dim3(33), dim3(256), 0, stream,
                       B, C, Dd, BtB, CtC, Cpk, Bpk, DBpk, flag);
    hipLaunchKernelGGL(k_A, dim3(1024), dim3(256), 0, stream,
                       k, v, Cpk, Bpk, DBpk, flag, kC_g, vB_g, eB_g);
    hipLaunchKernelGGL(k_mid, dim3(64), dim3(256), 0, stream,
                       kC_g, vB_g, eB_g, BtB, flag);
    hipLaunchKernelGGL(k_pack, dim3(128), dim3(256), 0, stream,
                       kC_g, eB_g, kCb, eBb);
    hipLaunchKernelGGL(k_T, dim3(2048), dim3(256), 0, stream,
                       k, v, kCb, eBb, flag, Ppart, Gpart, Qpart, S2, colsum);
    hipLaunchKernelGGL(k_ln, dim3(1), dim3(256), 0, stream, colsum, gam, bet, h1);
    hipLaunchKernelGGL(k_gemv, dim3(512), dim3(256), 0, stream, h1, W1, b1, h2);
    hipLaunchKernelGGL(k_alpha, dim3(1), dim3(256), 0, stream, h2, W2, b2, alphaW, outAlpha);
    hipLaunchKernelGGL(k_update, dim3(128), dim3(256), 0, stream,
                       B, C, Dd, S_B, S_C, Ppart, Gpart, Qpart, S2, CtC, BtB,
                       alphaW, flag, outB, outC, outSB, outSC);
    hipLaunchKernelGGL(k_ro, dim3(2048), dim3(256), 0, stream,
                       k, B, Dd, kC_g, flag, ro);
}

// Round 13
// 181.847 us; speedup vs baseline: 1.1463x; 1.0016x over previous
//
#include <hip/hip_runtime.h>
#include <hip/hip_bf16.h>
#include <math.h>

#define NROWS 16384
#define DM    2048
#define RK    16
#define LRc    1e-3f
#define L2c    1e-4f
#define MOMc   0.9f
#define SCALEc 0.1f
#define LNEPS  1e-5f

typedef __attribute__((ext_vector_type(8))) short short8;
typedef __attribute__((ext_vector_type(4))) float floatx4;

union U4S8 { uint4 u4; short8 s8; unsigned u[4]; };

__device__ inline unsigned pk2(float lo, float hi) {
    union { __hip_bfloat162 h; unsigned u; } cv;
    cv.h = __float22bfloat162_rn(make_float2(lo, hi));
    return cv.u;
}

// ---------------------------------------------------------------------------
// k_prep: blocks 0-15: BtB/CtC (atomic). blocks 16-31: pack B,C,D∘B into
// MFMA fragment layout. block 32: D!=0 flag.
// ---------------------------------------------------------------------------
__global__ __launch_bounds__(256) void k_prep(
    const float* __restrict__ B, const float* __restrict__ C,
    const float* __restrict__ Dd,
    float* __restrict__ BtB, float* __restrict__ CtC,
    uint4* __restrict__ Cpk, uint4* __restrict__ Bpk, uint4* __restrict__ DBpk,
    int* __restrict__ flag)
{
    const int bid = blockIdx.x, t = threadIdx.x;
    if (bid < 16) {
        const int a = t >> 4, b = t & 15;
        const int dBeg = bid * 128;
        float sc = 0.f, sb = 0.f;
        for (int d = dBeg; d < dBeg + 128; ++d) {
            sc += C[d * RK + a] * C[d * RK + b];
            sb += B[d * RK + a] * B[d * RK + b];
        }
        atomicAdd(CtC + a * RK + b, sc);
        atomicAdd(BtB + a * RK + b, sb);
    } else if (bid < 32) {
        const int idx = (bid - 16) * 256 + t;      // 4096 = 64 chunks x 64 lanes
        const int c = idx >> 6, l = idx & 63;
        const int dbase = c * 32 + (l >> 4) * 8;
        const int col = l & 15;
        U4S8 uc, ub, ud;
        #pragma unroll
        for (int q = 0; q < 4; ++q) {
            const int d0 = dbase + 2 * q, d1 = d0 + 1;
            uc.u[q] = pk2(C[d0 * RK + col], C[d1 * RK + col]);
            ub.u[q] = pk2(B[d0 * RK + col], B[d1 * RK + col]);
            ud.u[q] = pk2(Dd[d0] * B[d0 * RK + col], Dd[d1] * B[d1 * RK + col]);
        }
        Cpk[idx] = uc.u4; Bpk[idx] = ub.u4; DBpk[idx] = ud.u4;
    } else {
        __shared__ int sh;
        if (t == 0) sh = 0;
        __syncthreads();
        int any = 0;
        for (int i = t; i < DM; i += 256) any |= (Dd[i] != 0.f) ? 1 : 0;
        if (any) sh = 1;
        __syncthreads();
        if (t == 0) *flag = sh;
    }
}

// ---------------------------------------------------------------------------
// k_A: REGISTER-staged MFMA row-reductions (k_T's proven skeleton applied to
// the d-reduction): NO LDS in the hot loop -- global_load_lds forces the
// memory legalizer to emit vmcnt(0) before LDS reads (depth-0 pipeline, the
// invariant ~100us across R7-R12). Register deps get counted vmcnt instead.
// Depth-2 named buffers + sched_barrier(0) pinning (validated on k_T).
// Block = 16 rows x 2048 d, 4 waves; wave w: 16 chunks of 32 d (cc=w*16+j).
// Lane l: row m=l&15, d-octet g=l>>4 -> per-lane 2xfloat4 of k and v.
//   kC = k@C, vB = v@B, kDB = (k o D)@B (skipped when D==0).
// 1024 blocks x 256 thr. Epilogue: LDS cross-wave K-reduce (only barriers).
// ---------------------------------------------------------------------------
__global__ __launch_bounds__(256) void k_A(
    const float* __restrict__ k, const float* __restrict__ v,
    const uint4* __restrict__ Cpk, const uint4* __restrict__ Bpk,
    const uint4* __restrict__ DBpk, const int* __restrict__ flag,
    float* __restrict__ kC_g, float* __restrict__ vB_g, float* __restrict__ eB_g)
{
    __shared__ floatx4 red[3][4][64];   // 12 KB, epilogue only
    const int t = threadIdx.x;
    const int lane = t & 63;
    const int w = t >> 6;
    const int R0 = blockIdx.x * 16;
    const int m = lane & 15;
    const int g = lane >> 4;
    const int dnz = *flag;

    // per-lane base pointers: row R0+m, d = cc*32 + g*8
    const float* kp = k + (size_t)(R0 + m) * DM + g * 8;
    const float* vp = v + (size_t)(R0 + m) * DM + g * 8;
    const int cc0 = w * 16;

    floatx4 a0 = {0.f,0.f,0.f,0.f}, a1 = {0.f,0.f,0.f,0.f}, a2 = {0.f,0.f,0.f,0.f};

    // depth-2 preload: A = chunk 0, B = chunk 1 (per-wave chunk index j)
    float4 kaA = *(const float4*)(kp + (size_t)(cc0 + 0) * 32);
    float4 kbA = *(const float4*)(kp + (size_t)(cc0 + 0) * 32 + 4);
    float4 vaA = *(const float4*)(vp + (size_t)(cc0 + 0) * 32);
    float4 vbA = *(const float4*)(vp + (size_t)(cc0 + 0) * 32 + 4);
    uint4  cfA = Cpk[(cc0 + 0) * 64 + lane];
    uint4  bfA = Bpk[(cc0 + 0) * 64 + lane];
    uint4  dfA = make_uint4(0u,0u,0u,0u);
    float4 kaB = *(const float4*)(kp + (size_t)(cc0 + 1) * 32);
    float4 kbB = *(const float4*)(kp + (size_t)(cc0 + 1) * 32 + 4);
    float4 vaB = *(const float4*)(vp + (size_t)(cc0 + 1) * 32);
    float4 vbB = *(const float4*)(vp + (size_t)(cc0 + 1) * 32 + 4);
    uint4  cfB = Cpk[(cc0 + 1) * 64 + lane];
    uint4  bfB = Bpk[(cc0 + 1) * 64 + lane];
    uint4  dfB = make_uint4(0u,0u,0u,0u);
    if (dnz) { dfA = DBpk[(cc0 + 0) * 64 + lane]; dfB = DBpk[(cc0 + 1) * 64 + lane]; }
    __builtin_amdgcn_sched_barrier(0);

    #pragma unroll
    for (int j = 0; j < 16; j += 2) {
        // ---- even: consume A (chunk j), refill A <- chunk j+2 ----
        {
            U4S8 kf, vf, cu, bu, du;
            kf.u[0] = pk2(kaA.x, kaA.y); kf.u[1] = pk2(kaA.z, kaA.w);
            kf.u[2] = pk2(kbA.x, kbA.y); kf.u[3] = pk2(kbA.z, kbA.w);
            vf.u[0] = pk2(vaA.x, vaA.y); vf.u[1] = pk2(vaA.z, vaA.w);
            vf.u[2] = pk2(vbA.x, vbA.y); vf.u[3] = pk2(vbA.z, vbA.w);
            cu.u4 = cfA; bu.u4 = bfA; du.u4 = dfA;

            const int jn = (j + 2 < 16) ? j + 2 : j;
            kaA = *(const float4*)(kp + (size_t)(cc0 + jn) * 32);
            kbA = *(const float4*)(kp + (size_t)(cc0 + jn) * 32 + 4);
            vaA = *(const float4*)(vp + (size_t)(cc0 + jn) * 32);
            vbA = *(const float4*)(vp + (size_t)(cc0 + jn) * 32 + 4);
            cfA = Cpk[(cc0 + jn) * 64 + lane];
            bfA = Bpk[(cc0 + jn) * 64 + lane];
            if (dnz) dfA = DBpk[(cc0 + jn) * 64 + lane];
            __builtin_amdgcn_sched_barrier(0);   // pin refill issue here

            a0 = __builtin_amdgcn_mfma_f32_16x16x32_bf16(kf.s8, cu.s8, a0, 0, 0, 0);
            a1 = __builtin_amdgcn_mfma_f32_16x16x32_bf16(vf.s8, bu.s8, a1, 0, 0, 0);
            if (dnz)
                a2 = __builtin_amdgcn_mfma_f32_16x16x32_bf16(kf.s8, du.s8, a2, 0, 0, 0);
        }
        // ---- odd: consume B (chunk j+1), refill B <- chunk j+3 ----
        {
            U4S8 kf, vf, cu, bu, du;
            kf.u[0] = pk2(kaB.x, kaB.y); kf.u[1] = pk2(kaB.z, kaB.w);
            kf.u[2] = pk2(kbB.x, kbB.y); kf.u[3] = pk2(kbB.z, kbB.w);
            vf.u[0] = pk2(vaB.x, vaB.y); vf.u[1] = pk2(vaB.z, vaB.w);
            vf.u[2] = pk2(vbB.x, vbB.y); vf.u[3] = pk2(vbB.z, vbB.w);
            cu.u4 = cfB; bu.u4 = bfB; du.u4 = dfB;

            const int jn = (j + 3 < 16) ? j + 3 : j + 1;
            kaB = *(const float4*)(kp + (size_t)(cc0 + jn) * 32);
            kbB = *(const float4*)(kp + (size_t)(cc0 + jn) * 32 + 4);
            vaB = *(const float4*)(vp + (size_t)(cc0 + jn) * 32);
            vbB = *(const float4*)(vp + (size_t)(cc0 + jn) * 32 + 4);
            cfB = Cpk[(cc0 + jn) * 64 + lane];
            bfB = Bpk[(cc0 + jn) * 64 + lane];
            if (dnz) dfB = DBpk[(cc0 + jn) * 64 + lane];
            __builtin_amdgcn_sched_barrier(0);   // pin refill issue here

            a0 = __builtin_amdgcn_mfma_f32_16x16x32_bf16(kf.s8, cu.s8, a0, 0, 0, 0);
            a1 = __builtin_amdgcn_mfma_f32_16x16x32_bf16(vf.s8, bu.s8, a1, 0, 0, 0);
            if (dnz)
                a2 = __builtin_amdgcn_mfma_f32_16x16x32_bf16(kf.s8, du.s8, a2, 0, 0, 0);
        }
    }

    // cross-wave K-reduce (the ONLY barriers)
    red[0][w][lane] = a0;
    red[1][w][lane] = a1;
    red[2][w][lane] = a2;
    __syncthreads();
    if (w == 0) {
        const floatx4 s0 = red[0][0][lane] + red[0][1][lane] + red[0][2][lane] + red[0][3][lane];
        const floatx4 s1 = red[1][0][lane] + red[1][1][lane] + red[1][2][lane] + red[1][3][lane];
        const floatx4 s2 = red[2][0][lane] + red[2][1][lane] + red[2][2][lane] + red[2][3][lane];
        #pragma unroll
        for (int j = 0; j < 4; ++j) {
            const size_t o = (size_t)(R0 + g * 4 + j) * RK + m;
            kC_g[o] = s0[j];
            vB_g[o] = s1[j];
            if (dnz) eB_g[o] = s2[j];   // holds kDB until k_mid rewrites
        }
    }
}

// ---------------------------------------------------------------------------
// k_mid: errB = vB - kDB - 0.1*kC@BtB (in-place over eB_g). 64 blocks x 256.
// ---------------------------------------------------------------------------
__global__ __launch_bounds__(256) void k_mid(
    const float* __restrict__ kC_g, const float* __restrict__ vB_g,
    float* __restrict__ eB_g, const float* __restrict__ BtB,
    const int* __restrict__ flag)
{
    __shared__ float Bsh[256];
    const int t = threadIdx.x;
    Bsh[t] = BtB[t];
    __syncthreads();
    const int dnz = *flag;
    const int n = blockIdx.x * 256 + t;
    float kc[16], vb[16], kdb[16];
    #pragma unroll
    for (int q = 0; q < 4; ++q) {
        const float4 a = *(const float4*)(kC_g + (size_t)n * RK + q * 4);
        const float4 b = *(const float4*)(vB_g + (size_t)n * RK + q * 4);
        kc[q*4+0]=a.x; kc[q*4+1]=a.y; kc[q*4+2]=a.z; kc[q*4+3]=a.w;
        vb[q*4+0]=b.x; vb[q*4+1]=b.y; vb[q*4+2]=b.z; vb[q*4+3]=b.w;
        kdb[q*4+0]=0.f; kdb[q*4+1]=0.f; kdb[q*4+2]=0.f; kdb[q*4+3]=0.f;
    }
    if (dnz) {
        #pragma unroll
        for (int q = 0; q < 4; ++q) {
            const float4 c = *(const float4*)(eB_g + (size_t)n * RK + q * 4);
            kdb[q*4+0]=c.x; kdb[q*4+1]=c.y; kdb[q*4+2]=c.z; kdb[q*4+3]=c.w;
        }
    }
    float out[16];
    #pragma unroll
    for (int r = 0; r < 16; ++r) {
        float acc = 0.f;
        #pragma unroll
        for (int s = 0; s < 16; ++s) acc += kc[s] * Bsh[s * 16 + r];
        out[r] = vb[r] - kdb[r] - SCALEc * acc;
    }
    #pragma unroll
    for (int q = 0; q < 4; ++q)
        *(float4*)(eB_g + (size_t)n * RK + q * 4) =
            make_float4(out[q*4+0], out[q*4+1], out[q*4+2], out[q*4+3]);
}

// ---------------------------------------------------------------------------
// k_pack: pack kC^T, errB^T into MFMA A-fragments (bf16). 128 blocks x 256.
// ---------------------------------------------------------------------------
__global__ __launch_bounds__(256) void k_pack(
    const float* __restrict__ kC_g, const float* __restrict__ eB_g,
    uint4* __restrict__ kCb, uint4* __restrict__ eBb)
{
    const int idx = blockIdx.x * 256 + threadIdx.x;   // 0..32767
    const int c = idx >> 6, l = idx & 63;
    const int col = l & 15;
    const int nb = c * 32 + (l >> 4) * 8;
    U4S8 ah, bh;
    #pragma unroll
    for (int q = 0; q < 4; ++q) {
        const int n0 = nb + 2 * q;
        ah.u[q] = pk2(kC_g[(size_t)n0 * RK + col], kC_g[(size_t)(n0 + 1) * RK + col]);
        bh.u[q] = pk2(eB_g[(size_t)n0 * RK + col], eB_g[(size_t)(n0 + 1) * RK + col]);
    }
    kCb[idx] = ah.u4;
    eBb[idx] = bh.u4;
}

// ---------------------------------------------------------------------------
// k_T: tall reductions via MFMA, depth-2 prefetch pinned via sched_barrier.
// Plain (cacheable) loads so k/v stay L3-resident from k_A; NT stores for
// write-once partials.
//   Ppart[cgrp] = kC^T@v, Gpart[cgrp] = errB^T@k, Qpart[cgrp] = kC^T@k
//   S2 = kC^T@kC (dgrp==0 only), colsum (atomic).
// grid = 32 dgrp x 64 cgrp = 2048 blocks x 256 thr; wave: 16 d x 8 iters.
// ---------------------------------------------------------------------------
__global__ __launch_bounds__(256) void k_T(
    const float* __restrict__ k, const float* __restrict__ v,
    const uint4* __restrict__ kCb, const uint4* __restrict__ eBb,
    const int* __restrict__ flag,
    float* __restrict__ Ppart, float* __restrict__ Gpart, float* __restrict__ Qpart,
    float* __restrict__ S2, float* __restrict__ colsum)
{
    const int t = threadIdx.x;
    const int lane = t & 63;
    const int w = t >> 6;
    const int dgrp = blockIdx.x & 31;
    const int cgrp = blockIdx.x >> 5;          // 0..63
    const int d = dgrp * 64 + w * 16 + (lane & 15);
    const int rowoff = (lane >> 4) * 8;
    const int c0 = cgrp * 8;
    const int dnz = *flag;
    const int doS = (dgrp == 0);

    floatx4 accP = {0.f,0.f,0.f,0.f}, accG = {0.f,0.f,0.f,0.f};
    floatx4 accQ = {0.f,0.f,0.f,0.f}, accS = {0.f,0.f,0.f,0.f};
    float csl = 0.f;

    uint4 uKA = kCb[(size_t)c0 * 64 + lane];
    uint4 uEA = eBb[(size_t)c0 * 64 + lane];
    uint4 uKB = kCb[(size_t)(c0 + 1) * 64 + lane];
    uint4 uEB = eBb[(size_t)(c0 + 1) * 64 + lane];
    float knA[8], vnA[8], knB[8], vnB[8];
    {
        const float* kpA = k + ((size_t)(c0 * 32 + rowoff)) * DM + d;
        const float* vpA = v + ((size_t)(c0 * 32 + rowoff)) * DM + d;
        const float* kpB = kpA + (size_t)32 * DM;
        const float* vpB = vpA + (size_t)32 * DM;
        #pragma unroll
        for (int e = 0; e < 8; ++e) {
            knA[e] = kpA[(size_t)e * DM];
            vnA[e] = vpA[(size_t)e * DM];
            knB[e] = kpB[(size_t)e * DM];
            vnB[e] = vpB[(size_t)e * DM];
        }
        __builtin_amdgcn_sched_barrier(0);
    }

    #pragma unroll
    for (int cc = 0; cc < 8; cc += 2) {
        {
            U4S8 uK, uE, kf, vf;
            uK.u4 = uKA; uE.u4 = uEA;
            kf.u[0] = pk2(knA[0], knA[1]); kf.u[1] = pk2(knA[2], knA[3]);
            kf.u[2] = pk2(knA[4], knA[5]); kf.u[3] = pk2(knA[6], knA[7]);
            vf.u[0] = pk2(vnA[0], vnA[1]); vf.u[1] = pk2(vnA[2], vnA[3]);
            vf.u[2] = pk2(vnA[4], vnA[5]); vf.u[3] = pk2(vnA[6], vnA[7]);
            csl += knA[0] + knA[1] + knA[2] + knA[3]
                 + knA[4] + knA[5] + knA[6] + knA[7];

            const int cn = c0 + ((cc + 2 < 8) ? cc + 2 : cc);
            const float* kp = k + ((size_t)(cn * 32 + rowoff)) * DM + d;
            const float* vp = v + ((size_t)(cn * 32 + rowoff)) * DM + d;
            #pragma unroll
            for (int e = 0; e < 8; ++e) {
                knA[e] = kp[(size_t)e * DM];
                vnA[e] = vp[(size_t)e * DM];
            }
            uKA = kCb[(size_t)cn * 64 + lane];
            uEA = eBb[(size_t)cn * 64 + lane];
            __builtin_amdgcn_sched_barrier(0);   // pin refill issue here

            accP = __builtin_amdgcn_mfma_f32_16x16x32_bf16(uK.s8, vf.s8, accP, 0, 0, 0);
            accG = __builtin_amdgcn_mfma_f32_16x16x32_bf16(uE.s8, kf.s8, accG, 0, 0, 0);
            if (dnz)
                accQ = __builtin_amdgcn_mfma_f32_16x16x32_bf16(uK.s8, kf.s8, accQ, 0, 0, 0);
            if (doS)
                accS = __builtin_amdgcn_mfma_f32_16x16x32_bf16(uK.s8, uK.s8, accS, 0, 0, 0);
        }
        {
            U4S8 uK, uE, kf, vf;
            uK.u4 = uKB; uE.u4 = uEB;
            kf.u[0] = pk2(knB[0], knB[1]); kf.u[1] = pk2(knB[2], knB[3]);
            kf.u[2] = pk2(knB[4], knB[5]); kf.u[3] = pk2(knB[6], knB[7]);
            vf.u[0] = pk2(vnB[0], vnB[1]); vf.u[1] = pk2(vnB[2], vnB[3]);
            vf.u[2] = pk2(vnB[4], vnB[5]); vf.u[3] = pk2(vnB[6], vnB[7]);
            csl += knB[0] + knB[1] + knB[2] + knB[3]
                 + knB[4] + knB[5] + knB[6] + knB[7];

            const int cn = c0 + ((cc + 3 < 8) ? cc + 3 : cc + 1);
            const float* kp = k + ((size_t)(cn * 32 + rowoff)) * DM + d;
            const float* vp = v + ((size_t)(cn * 32 + rowoff)) * DM + d;
            #pragma unroll
            for (int e = 0; e < 8; ++e) {
                knB[e] = kp[(size_t)e * DM];
                vnB[e] = vp[(size_t)e * DM];
            }
            uKB = kCb[(size_t)cn * 64 + lane];
            uEB = eBb[(size_t)cn * 64 + lane];
            __builtin_amdgcn_sched_barrier(0);   // pin refill issue here

            accP = __builtin_amdgcn_mfma_f32_16x16x32_bf16(uK.s8, vf.s8, accP, 0, 0, 0);
            accG = __builtin_amdgcn_mfma_f32_16x16x32_bf16(uE.s8, kf.s8, accG, 0, 0, 0);
            if (dnz)
                accQ = __builtin_amdgcn_mfma_f32_16x16x32_bf16(uK.s8, kf.s8, accQ, 0, 0, 0);
            if (doS)
                accS = __builtin_amdgcn_mfma_f32_16x16x32_bf16(uK.s8, uK.s8, accS, 0, 0, 0);
        }
    }

    const int r0 = (lane >> 4) * 4;
    const size_t o = ((size_t)cgrp * DM + d) * RK + r0;
    __builtin_nontemporal_store(accP, (floatx4*)(Ppart + o));
    __builtin_nontemporal_store(accG, (floatx4*)(Gpart + o));
    if (dnz)
        __builtin_nontemporal_store(accQ, (floatx4*)(Qpart + o));

    if (doS && w == 0) {
        #pragma unroll
        for (int j = 0; j < 4; ++j)
            atomicAdd(S2 + (r0 + j) * RK + (lane & 15), accS[j]);
    }
    csl += __shfl_xor(csl, 16);
    csl += __shfl_xor(csl, 32);
    if ((lane >> 4) == 0) atomicAdd(colsum + d, csl);
}

// ---------------------------------------------------------------------------
// k_ro: ro[n,d] = 0.1*kC[n,:].B[d,:] (+ k*D if flag). Runs LAST (ro region
// doubles as partial-scratch until k_update consumes it). NT stores.
// ---------------------------------------------------------------------------
__global__ __launch_bounds__(256) void k_ro(
    const float* __restrict__ k, const float* __restrict__ B,
    const float* __restrict__ Dd, const float* __restrict__ kC_g,
    const int* __restrict__ flag, float* __restrict__ ro)
{
    __shared__ float kCch[16 * 16];
    const int t = threadIdx.x;
    const int slab = blockIdx.x & 1;
    const int chunk = blockIdx.x >> 1;
    const int d0 = slab * 1024 + t * 4;
    const int row0 = chunk * 16;
    const int dnz = *flag;

    float Breg[4][16], Dreg[4];
    #pragma unroll
    for (int i = 0; i < 4; ++i) {
        #pragma unroll
        for (int q = 0; q < 4; ++q) {
            const float4 b4 = *(const float4*)(B + (size_t)(d0 + i) * RK + q * 4);
            Breg[i][q*4+0] = b4.x; Breg[i][q*4+1] = b4.y;
            Breg[i][q*4+2] = b4.z; Breg[i][q*4+3] = b4.w;
        }
        Dreg[i] = Dd[d0 + i];
    }
    if (t < 64) *(float4*)&kCch[t * 4] = *(const float4*)(kC_g + (size_t)row0 * RK + t * 4);
    __syncthreads();

    float4 k0 = make_float4(0.f,0.f,0.f,0.f), k1 = k0;
    if (dnz) {
        k0 = *(const float4*)(k + (size_t)row0 * DM + d0);
        k1 = *(const float4*)(k + (size_t)(row0 + 1) * DM + d0);
    }

    for (int rr = 0; rr < 16; ++rr) {
        const int n = row0 + rr;
        const float4 kc4 = k0;
        if (dnz) {
            const int np = row0 + ((rr + 2 < 16) ? rr + 2 : 15);
            k0 = k1; k1 = *(const float4*)(k + (size_t)np * DM + d0);
        }
        float kcr[16];
        #pragma unroll
        for (int q = 0; q < 4; ++q) {
            const float4 c4 = *(const float4*)&kCch[rr * 16 + q * 4];
            kcr[q*4+0] = c4.x; kcr[q*4+1] = c4.y; kcr[q*4+2] = c4.z; kcr[q*4+3] = c4.w;
        }
        floatx4 roa;
        const float ka4[4] = {kc4.x, kc4.y, kc4.z, kc4.w};
        #pragma unroll
        for (int i = 0; i < 4; ++i) {
            float s = 0.f;
            #pragma unroll
            for (int r = 0; r < 16; ++r) s += kcr[r] * Breg[i][r];
            roa[i] = SCALEc * s;
            if (dnz) roa[i] += ka4[i] * Dreg[i];
        }
        __builtin_nontemporal_store(roa, (floatx4*)(ro + (size_t)n * DM + d0));
    }
}

// ---------------------------------------------------------------------------
// k_ln: k_mean = colsum/N; h1 = LayerNorm(k_mean)*gamma + beta.
// ---------------------------------------------------------------------------
__global__ __launch_bounds__(256) void k_ln(
    const float* __restrict__ colsum,
    const float* __restrict__ gam, const float* __restrict__ bet,
    float* __restrict__ h1)
{
    __shared__ float red[256];
    __shared__ float mu_sh, var_sh;
    const int t = threadIdx.x;
    float x[8];
    float s = 0.f;
    #pragma unroll
    for (int i = 0; i < 8; ++i) {
        x[i] = colsum[t + 256 * i] * (1.0f / (float)NROWS);
        s += x[i];
    }
    red[t] = s; __syncthreads();
    for (int off = 128; off > 0; off >>= 1) {
        if (t < off) red[t] += red[t + off];
        __syncthreads();
    }
    if (t == 0) mu_sh = red[0] * (1.0f / (float)DM);
    __syncthreads();
    const float mu = mu_sh;
    float s2 = 0.f;
    #pragma unroll
    for (int i = 0; i < 8; ++i) { const float dd = x[i] - mu; s2 += dd * dd; }
    __syncthreads();
    red[t] = s2; __syncthreads();
    for (int off = 128; off > 0; off >>= 1) {
        if (t < off) red[t] += red[t + off];
        __syncthreads();
    }
    if (t == 0) var_sh = red[0] * (1.0f / (float)DM);
    __syncthreads();
    const float rstd = rsqrtf(var_sh + LNEPS);
    #pragma unroll
    for (int i = 0; i < 8; ++i) {
        const int d = t + 256 * i;
        h1[d] = (x[i] - mu) * rstd * gam[d] + bet[d];
    }
}

// ---------------------------------------------------------------------------
// k_gemv: h2[i] = silu(h1 . W1[i,:] + b1[i]). 512 blocks x 256 (wave/row).
// ---------------------------------------------------------------------------
__global__ __launch_bounds__(256) void k_gemv(
    const float* __restrict__ h1, const float* __restrict__ W1,
    const float* __restrict__ b1, float* __restrict__ h2)
{
    const int t = threadIdx.x;
    const int lane = t & 63;
    const int w = t >> 6;
    const int row = blockIdx.x * 4 + w;
    const float* wr = W1 + (size_t)row * DM;
    float s = 0.f;
    #pragma unroll
    for (int j = 0; j < 8; ++j) {
        const float4 a = *(const float4*)(wr + j * 256 + lane * 4);
        const float4 b = *(const float4*)(h1 + j * 256 + lane * 4);
        s += a.x * b.x + a.y * b.y + a.z * b.z + a.w * b.w;
    }
    #pragma unroll
    for (int off = 32; off > 0; off >>= 1) s += __shfl_down(s, off);
    if (lane == 0) {
        const float val = s + b1[row];
        h2[row] = val / (1.0f + expf(-val));
    }
}

// ---------------------------------------------------------------------------
// k_alpha: alpha = sigmoid(h2 . W2 + b2).
// ---------------------------------------------------------------------------
__global__ __launch_bounds__(256) void k_alpha(
    const float* __restrict__ h2, const float* __restrict__ W2,
    const float* __restrict__ b2,
    float* __restrict__ alpha_ws, float* __restrict__ out_alpha)
{
    __shared__ float red[256];
    const int t = threadIdx.x;
    float s = 0.f;
    for (int i = t; i < DM; i += 256) s += h2[i] * W2[i];
    red[t] = s; __syncthreads();
    for (int off = 128; off > 0; off >>= 1) {
        if (t < off) red[t] += red[t + off];
        __syncthreads();
    }
    if (t == 0) {
        const float logit = red[0] + b2[0];
        const float a = 1.0f / (1.0f + expf(-logit));
        alpha_ws[0] = a;
        out_alpha[0] = a;
    }
}

// ---------------------------------------------------------------------------
// k_update: sum 64 partials; G1 = P1 - 0.1*B@S2 - D o Q; grads, momentum,
// B/C update. 128 blocks x 256.
// ---------------------------------------------------------------------------
__global__ __launch_bounds__(256) void k_update(
    const float* __restrict__ B, const float* __restrict__ C,
    const float* __restrict__ Dd,
    const float* __restrict__ S_B, const float* __restrict__ S_C,
    const float* __restrict__ Ppart, const float* __restrict__ Gpart,
    const float* __restrict__ Qpart, const float* __restrict__ S2,
    const float* __restrict__ CtC, const float* __restrict__ BtB,
    const float* __restrict__ alpha_ws, const int* __restrict__ flag,
    float* __restrict__ outB, float* __restrict__ outC,
    float* __restrict__ outSB, float* __restrict__ outSC)
{
    const int idx = blockIdx.x * 256 + threadIdx.x;   // [0, 32768)
    const int d = idx >> 4, r = idx & 15;
    const float alpha = alpha_ws[0];
    const int dnz = *flag;

    float P1v = 0.f, G2v = 0.f, Qv = 0.f;
    const size_t SL = (size_t)DM * RK;
    for (int p = 0; p < 64; ++p) {
        P1v += Ppart[(size_t)p * SL + idx];
        G2v += Gpart[(size_t)p * SL + idx];
    }
    if (dnz)
        for (int p = 0; p < 64; ++p) Qv += Qpart[(size_t)p * SL + idx];

    float Brow[16], Crow[16];
    #pragma unroll
    for (int q = 0; q < 4; ++q) {
        const float4 b4 = *(const float4*)(B + (size_t)d * RK + q * 4);
        const float4 c4 = *(const float4*)(C + (size_t)d * RK + q * 4);
        Brow[q*4+0] = b4.x; Brow[q*4+1] = b4.y; Brow[q*4+2] = b4.z; Brow[q*4+3] = b4.w;
        Crow[q*4+0] = c4.x; Crow[q*4+1] = c4.y; Crow[q*4+2] = c4.z; Crow[q*4+3] = c4.w;
    }
    float bc = 0.f, cb = 0.f, bs2 = 0.f;
    #pragma unroll
    for (int a = 0; a < 16; ++a) {
        bc  += Brow[a] * CtC[a * RK + r];
        cb  += Crow[a] * BtB[a * RK + r];
        bs2 += Brow[a] * S2[a * RK + r];
    }
    const float Ddv = Dd[d];
    const float invN = 1.0f / (float)NROWS;
    const float G1v = P1v - SCALEc * bs2 - Ddv * Qv;
    const float gradB = -G1v * invN + L2c * (SCALEc * bc + Ddv * Crow[r]);
    const float gradC = -G2v * invN + L2c * (SCALEc * cb + Ddv * Brow[r]);
    const float sB = MOMc * S_B[idx] - LRc * gradB;
    const float sC = MOMc * S_C[idx] - LRc * gradC;
    outSB[idx] = sB;
    outSC[idx] = sC;
    outB[idx] = (1.0f - alpha) * B[idx] + sB;
    outC[idx] = (1.0f - alpha) * C[idx] + sC;
}

// ---------------------------------------------------------------------------
extern "C" void kernel_launch(void* const* d_in, const int* in_sizes, int n_in,
                              void* d_out, int out_size, void* d_ws, size_t ws_size,
                              hipStream_t stream)
{
    const float* k   = (const float*)d_in[0];
    const float* v   = (const float*)d_in[1];
    const float* B   = (const float*)d_in[2];
    const float* C   = (const float*)d_in[3];
    const float* Dd  = (const float*)d_in[4];
    const float* S_B = (const float*)d_in[5];
    const float* S_C = (const float*)d_in[6];
    const float* gam = (const float*)d_in[7];
    const float* bet = (const float*)d_in[8];
    const float* W1  = (const float*)d_in[9];
    const float* b1  = (const float*)d_in[10];
    const float* W2  = (const float*)d_in[11];
    const float* b2  = (const float*)d_in[12];

    float* out      = (float*)d_out;
    float* ro       = out;                                  // [N, D] (written LAST)
    float* outB     = out + (size_t)NROWS * DM;
    float* outC     = outB + (size_t)DM * RK;
    float* outSB    = outC + (size_t)DM * RK;
    float* outSC    = outSB + (size_t)DM * RK;
    float* outAlpha = outSC + (size_t)DM * RK;

    // partial slabs live in the (not-yet-written) ro region: 64 x 32768 each
    float* Ppart = ro;                                      // 2,097,152 floats
    float* Gpart = Ppart + (size_t)64 * DM * RK;            // 2,097,152
    float* Qpart = Gpart + (size_t)64 * DM * RK;            // 2,097,152 (24 MB)

    float* ws = (float*)d_ws;
    float* kC_g   = ws;                                     // 262144
    float* vB_g   = kC_g + (size_t)NROWS * RK;              // 262144
    float* eB_g   = vB_g + (size_t)NROWS * RK;              // 262144 (kDB -> errB)
    float* S2     = eB_g + (size_t)NROWS * RK;              // 256 -- zero start
    float* CtC    = S2 + 256;                               // 256
    float* BtB    = CtC + 256;                              // 256
    float* colsum = BtB + 256;                              // 2048 -- zero end
    float* h1     = colsum + DM;                            // 2048
    float* h2     = h1 + DM;                                // 2048
    uint4* Cpk    = (uint4*)(h2 + DM);                      // 4096 uint4
    uint4* Bpk    = Cpk + 4096;
    uint4* DBpk   = Bpk + 4096;
    uint4* kCb    = DBpk + 4096;                            // 32768 uint4
    uint4* eBb    = kCb + 32768;                            // 32768 uint4
    float* alphaW = (float*)(eBb + 32768);
    int*   flag   = (int*)(alphaW + 1);

    // zero only S2/CtC/BtB/colsum: 2816 floats
    hipMemsetAsync(S2, 0, (size_t)2816 * sizeof(float), stream);

    hipLaunchKernelGGL(k_prep, dim3(33), dim3(256), 0, stream,
                       B, C, Dd, BtB, CtC, Cpk, Bpk, DBpk, flag);
    hipLaunchKernelGGL(k_A, dim3(1024), dim3(256), 0, stream,
                       k, v, Cpk, Bpk, DBpk, flag, kC_g, vB_g, eB_g);
    hipLaunchKernelGGL(k_mid, dim3(64), dim3(256), 0, stream,
                       kC_g, vB_g, eB_g, BtB, flag);
    hipLaunchKernelGGL(k_pack, dim3(128), dim3(256), 0, stream,
                       kC_g, eB_g, kCb, eBb);
    hipLaunchKernelGGL(k_T, dim3(2048), dim3(256), 0, stream,
                       k, v, kCb, eBb, flag, Ppart, Gpart, Qpart, S2, colsum);
    hipLaunchKernelGGL(k_ln, dim3(1), dim3(256), 0, stream, colsum, gam, bet, h1);
    hipLaunchKernelGGL(k_gemv, dim3(512), dim3(256), 0, stream, h1, W1, b1, h2);
    hipLaunchKernelGGL(k_alpha, dim3(1), dim3(256), 0, stream, h2, W2, b2, alphaW, outAlpha);
    hipLaunchKernelGGL(k_update, dim3(128), dim3(256), 0, stream,
                       B, C, Dd, S_B, S_C, Ppart, Gpart, Qpart, S2, CtC, BtB,
                       alphaW, flag, outB, outC, outSB, outSC);
    hipLaunchKernelGGL(k_ro, dim3(2048), dim3(256), 0, stream,
                       k, B, Dd, kC_g, flag, ro);
}

// Round 14
// 179.487 us; speedup vs baseline: 1.1613x; 1.0131x over previous
//
#include <hip/hip_runtime.h>
#include <hip/hip_bf16.h>
#include <math.h>

#define NROWS 16384
#define DM    2048
#define RK    16
#define LRc    1e-3f
#define L2c    1e-4f
#define MOMc   0.9f
#define SCALEc 0.1f
#define LNEPS  1e-5f

typedef __attribute__((ext_vector_type(8))) short short8;
typedef __attribute__((ext_vector_type(4))) float floatx4;

union U4S8 { uint4 u4; short8 s8; unsigned u[4]; };

__device__ inline unsigned pk2(float lo, float hi) {
    union { __hip_bfloat162 h; unsigned u; } cv;
    cv.h = __float22bfloat162_rn(make_float2(lo, hi));
    return cv.u;
}

// ---------------------------------------------------------------------------
// k_prep: blocks 0-15: BtB/CtC (atomic). blocks 16-31: pack B,C,D∘B into
// MFMA fragment layout. block 32: D!=0 flag.
// ---------------------------------------------------------------------------
__global__ __launch_bounds__(256) void k_prep(
    const float* __restrict__ B, const float* __restrict__ C,
    const float* __restrict__ Dd,
    float* __restrict__ BtB, float* __restrict__ CtC,
    uint4* __restrict__ Cpk, uint4* __restrict__ Bpk, uint4* __restrict__ DBpk,
    int* __restrict__ flag)
{
    const int bid = blockIdx.x, t = threadIdx.x;
    if (bid < 16) {
        const int a = t >> 4, b = t & 15;
        const int dBeg = bid * 128;
        float sc = 0.f, sb = 0.f;
        for (int d = dBeg; d < dBeg + 128; ++d) {
            sc += C[d * RK + a] * C[d * RK + b];
            sb += B[d * RK + a] * B[d * RK + b];
        }
        atomicAdd(CtC + a * RK + b, sc);
        atomicAdd(BtB + a * RK + b, sb);
    } else if (bid < 32) {
        const int idx = (bid - 16) * 256 + t;      // 4096 = 64 chunks x 64 lanes
        const int c = idx >> 6, l = idx & 63;
        const int dbase = c * 32 + (l >> 4) * 8;
        const int col = l & 15;
        U4S8 uc, ub, ud;
        #pragma unroll
        for (int q = 0; q < 4; ++q) {
            const int d0 = dbase + 2 * q, d1 = d0 + 1;
            uc.u[q] = pk2(C[d0 * RK + col], C[d1 * RK + col]);
            ub.u[q] = pk2(B[d0 * RK + col], B[d1 * RK + col]);
            ud.u[q] = pk2(Dd[d0] * B[d0 * RK + col], Dd[d1] * B[d1 * RK + col]);
        }
        Cpk[idx] = uc.u4; Bpk[idx] = ub.u4; DBpk[idx] = ud.u4;
    } else {
        __shared__ int sh;
        if (t == 0) sh = 0;
        __syncthreads();
        int any = 0;
        for (int i = t; i < DM; i += 256) any |= (Dd[i] != 0.f) ? 1 : 0;
        if (any) sh = 1;
        __syncthreads();
        if (t == 0) *flag = sh;
    }
}

// ---------------------------------------------------------------------------
// k_A: REGISTER-staged MFMA row-reductions, depth-2 named buffers pinned with
// sched_barrier(0). KEY CHANGE vs R13: __launch_bounds__(256, 2) -- the bare
// (256) let the allocator target 8 waves/SIMD (<=64 VGPR, measured 60), which
// CANNOT hold the depth-2 buffers (~110 regs) -> silent serialization, the
// invariant ~96us across R7-R13. (256,2) allows ~256 VGPR/wave; 8 waves/CU of
// TLP remain, ILP provides the rest.
// Block = 16 rows x 2048 d, 4 waves; wave w: 16 chunks of 32 d (cc=w*16+j).
//   kC = k@C, vB = v@B, kDB = (k o D)@B (skipped when D==0).
// 1024 blocks x 256 thr. Epilogue: LDS cross-wave K-reduce (only barriers).
// ---------------------------------------------------------------------------
__global__ __launch_bounds__(256, 2) void k_A(
    const float* __restrict__ k, const float* __restrict__ v,
    const uint4* __restrict__ Cpk, const uint4* __restrict__ Bpk,
    const uint4* __restrict__ DBpk, const int* __restrict__ flag,
    float* __restrict__ kC_g, float* __restrict__ vB_g, float* __restrict__ eB_g)
{
    __shared__ floatx4 red[3][4][64];   // 12 KB, epilogue only
    const int t = threadIdx.x;
    const int lane = t & 63;
    const int w = t >> 6;
    const int R0 = blockIdx.x * 16;
    const int m = lane & 15;
    const int g = lane >> 4;
    const int dnz = *flag;

    // per-lane base pointers: row R0+m, d = cc*32 + g*8
    const float* kp = k + (size_t)(R0 + m) * DM + g * 8;
    const float* vp = v + (size_t)(R0 + m) * DM + g * 8;
    const int cc0 = w * 16;

    floatx4 a0 = {0.f,0.f,0.f,0.f}, a1 = {0.f,0.f,0.f,0.f}, a2 = {0.f,0.f,0.f,0.f};

    // depth-2 preload: A = chunk 0, B = chunk 1 (per-wave chunk index j)
    float4 kaA = *(const float4*)(kp + (size_t)(cc0 + 0) * 32);
    float4 kbA = *(const float4*)(kp + (size_t)(cc0 + 0) * 32 + 4);
    float4 vaA = *(const float4*)(vp + (size_t)(cc0 + 0) * 32);
    float4 vbA = *(const float4*)(vp + (size_t)(cc0 + 0) * 32 + 4);
    uint4  cfA = Cpk[(cc0 + 0) * 64 + lane];
    uint4  bfA = Bpk[(cc0 + 0) * 64 + lane];
    uint4  dfA = make_uint4(0u,0u,0u,0u);
    float4 kaB = *(const float4*)(kp + (size_t)(cc0 + 1) * 32);
    float4 kbB = *(const float4*)(kp + (size_t)(cc0 + 1) * 32 + 4);
    float4 vaB = *(const float4*)(vp + (size_t)(cc0 + 1) * 32);
    float4 vbB = *(const float4*)(vp + (size_t)(cc0 + 1) * 32 + 4);
    uint4  cfB = Cpk[(cc0 + 1) * 64 + lane];
    uint4  bfB = Bpk[(cc0 + 1) * 64 + lane];
    uint4  dfB = make_uint4(0u,0u,0u,0u);
    if (dnz) { dfA = DBpk[(cc0 + 0) * 64 + lane]; dfB = DBpk[(cc0 + 1) * 64 + lane]; }
    __builtin_amdgcn_sched_barrier(0);

    #pragma unroll
    for (int j = 0; j < 16; j += 2) {
        // ---- even: consume A (chunk j), refill A <- chunk j+2 ----
        {
            U4S8 kf, vf, cu, bu, du;
            kf.u[0] = pk2(kaA.x, kaA.y); kf.u[1] = pk2(kaA.z, kaA.w);
            kf.u[2] = pk2(kbA.x, kbA.y); kf.u[3] = pk2(kbA.z, kbA.w);
            vf.u[0] = pk2(vaA.x, vaA.y); vf.u[1] = pk2(vaA.z, vaA.w);
            vf.u[2] = pk2(vbA.x, vbA.y); vf.u[3] = pk2(vbA.z, vbA.w);
            cu.u4 = cfA; bu.u4 = bfA; du.u4 = dfA;

            const int jn = (j + 2 < 16) ? j + 2 : j;
            kaA = *(const float4*)(kp + (size_t)(cc0 + jn) * 32);
            kbA = *(const float4*)(kp + (size_t)(cc0 + jn) * 32 + 4);
            vaA = *(const float4*)(vp + (size_t)(cc0 + jn) * 32);
            vbA = *(const float4*)(vp + (size_t)(cc0 + jn) * 32 + 4);
            cfA = Cpk[(cc0 + jn) * 64 + lane];
            bfA = Bpk[(cc0 + jn) * 64 + lane];
            if (dnz) dfA = DBpk[(cc0 + jn) * 64 + lane];
            __builtin_amdgcn_sched_barrier(0);   // pin refill issue here

            a0 = __builtin_amdgcn_mfma_f32_16x16x32_bf16(kf.s8, cu.s8, a0, 0, 0, 0);
            a1 = __builtin_amdgcn_mfma_f32_16x16x32_bf16(vf.s8, bu.s8, a1, 0, 0, 0);
            if (dnz)
                a2 = __builtin_amdgcn_mfma_f32_16x16x32_bf16(kf.s8, du.s8, a2, 0, 0, 0);
        }
        // ---- odd: consume B (chunk j+1), refill B <- chunk j+3 ----
        {
            U4S8 kf, vf, cu, bu, du;
            kf.u[0] = pk2(kaB.x, kaB.y); kf.u[1] = pk2(kaB.z, kaB.w);
            kf.u[2] = pk2(kbB.x, kbB.y); kf.u[3] = pk2(kbB.z, kbB.w);
            vf.u[0] = pk2(vaB.x, vaB.y); vf.u[1] = pk2(vaB.z, vaB.w);
            vf.u[2] = pk2(vbB.x, vbB.y); vf.u[3] = pk2(vbB.z, vbB.w);
            cu.u4 = cfB; bu.u4 = bfB; du.u4 = dfB;

            const int jn = (j + 3 < 16) ? j + 3 : j + 1;
            kaB = *(const float4*)(kp + (size_t)(cc0 + jn) * 32);
            kbB = *(const float4*)(kp + (size_t)(cc0 + jn) * 32 + 4);
            vaB = *(const float4*)(vp + (size_t)(cc0 + jn) * 32);
            vbB = *(const float4*)(vp + (size_t)(cc0 + jn) * 32 + 4);
            cfB = Cpk[(cc0 + jn) * 64 + lane];
            bfB = Bpk[(cc0 + jn) * 64 + lane];
            if (dnz) dfB = DBpk[(cc0 + jn) * 64 + lane];
            __builtin_amdgcn_sched_barrier(0);   // pin refill issue here

            a0 = __builtin_amdgcn_mfma_f32_16x16x32_bf16(kf.s8, cu.s8, a0, 0, 0, 0);
            a1 = __builtin_amdgcn_mfma_f32_16x16x32_bf16(vf.s8, bu.s8, a1, 0, 0, 0);
            if (dnz)
                a2 = __builtin_amdgcn_mfma_f32_16x16x32_bf16(kf.s8, du.s8, a2, 0, 0, 0);
        }
    }

    // cross-wave K-reduce (the ONLY barriers)
    red[0][w][lane] = a0;
    red[1][w][lane] = a1;
    red[2][w][lane] = a2;
    __syncthreads();
    if (w == 0) {
        const floatx4 s0 = red[0][0][lane] + red[0][1][lane] + red[0][2][lane] + red[0][3][lane];
        const floatx4 s1 = red[1][0][lane] + red[1][1][lane] + red[1][2][lane] + red[1][3][lane];
        const floatx4 s2 = red[2][0][lane] + red[2][1][lane] + red[2][2][lane] + red[2][3][lane];
        #pragma unroll
        for (int j = 0; j < 4; ++j) {
            const size_t o = (size_t)(R0 + g * 4 + j) * RK + m;
            kC_g[o] = s0[j];
            vB_g[o] = s1[j];
            if (dnz) eB_g[o] = s2[j];   // holds kDB until k_mid rewrites
        }
    }
}

// ---------------------------------------------------------------------------
// k_mid: errB = vB - kDB - 0.1*kC@BtB (in-place over eB_g). 64 blocks x 256.
// ---------------------------------------------------------------------------
__global__ __launch_bounds__(256) void k_mid(
    const float* __restrict__ kC_g, const float* __restrict__ vB_g,
    float* __restrict__ eB_g, const float* __restrict__ BtB,
    const int* __restrict__ flag)
{
    __shared__ float Bsh[256];
    const int t = threadIdx.x;
    Bsh[t] = BtB[t];
    __syncthreads();
    const int dnz = *flag;
    const int n = blockIdx.x * 256 + t;
    float kc[16], vb[16], kdb[16];
    #pragma unroll
    for (int q = 0; q < 4; ++q) {
        const float4 a = *(const float4*)(kC_g + (size_t)n * RK + q * 4);
        const float4 b = *(const float4*)(vB_g + (size_t)n * RK + q * 4);
        kc[q*4+0]=a.x; kc[q*4+1]=a.y; kc[q*4+2]=a.z; kc[q*4+3]=a.w;
        vb[q*4+0]=b.x; vb[q*4+1]=b.y; vb[q*4+2]=b.z; vb[q*4+3]=b.w;
        kdb[q*4+0]=0.f; kdb[q*4+1]=0.f; kdb[q*4+2]=0.f; kdb[q*4+3]=0.f;
    }
    if (dnz) {
        #pragma unroll
        for (int q = 0; q < 4; ++q) {
            const float4 c = *(const float4*)(eB_g + (size_t)n * RK + q * 4);
            kdb[q*4+0]=c.x; kdb[q*4+1]=c.y; kdb[q*4+2]=c.z; kdb[q*4+3]=c.w;
        }
    }
    float out[16];
    #pragma unroll
    for (int r = 0; r < 16; ++r) {
        float acc = 0.f;
        #pragma unroll
        for (int s = 0; s < 16; ++s) acc += kc[s] * Bsh[s * 16 + r];
        out[r] = vb[r] - kdb[r] - SCALEc * acc;
    }
    #pragma unroll
    for (int q = 0; q < 4; ++q)
        *(float4*)(eB_g + (size_t)n * RK + q * 4) =
            make_float4(out[q*4+0], out[q*4+1], out[q*4+2], out[q*4+3]);
}

// ---------------------------------------------------------------------------
// k_pack: pack kC^T, errB^T into MFMA A-fragments (bf16). 128 blocks x 256.
// ---------------------------------------------------------------------------
__global__ __launch_bounds__(256) void k_pack(
    const float* __restrict__ kC_g, const float* __restrict__ eB_g,
    uint4* __restrict__ kCb, uint4* __restrict__ eBb)
{
    const int idx = blockIdx.x * 256 + threadIdx.x;   // 0..32767
    const int c = idx >> 6, l = idx & 63;
    const int col = l & 15;
    const int nb = c * 32 + (l >> 4) * 8;
    U4S8 ah, bh;
    #pragma unroll
    for (int q = 0; q < 4; ++q) {
        const int n0 = nb + 2 * q;
        ah.u[q] = pk2(kC_g[(size_t)n0 * RK + col], kC_g[(size_t)(n0 + 1) * RK + col]);
        bh.u[q] = pk2(eB_g[(size_t)n0 * RK + col], eB_g[(size_t)(n0 + 1) * RK + col]);
    }
    kCb[idx] = ah.u4;
    eBb[idx] = bh.u4;
}

// ---------------------------------------------------------------------------
// k_T: tall reductions via MFMA, depth-2 prefetch pinned via sched_barrier.
// Plain (cacheable) loads so k/v stay L3-resident from k_A; NT stores for
// write-once partials.
//   Ppart[cgrp] = kC^T@v, Gpart[cgrp] = errB^T@k, Qpart[cgrp] = kC^T@k
//   S2 = kC^T@kC (dgrp==0 only), colsum (atomic).
// grid = 32 dgrp x 64 cgrp = 2048 blocks x 256 thr; wave: 16 d x 8 iters.
// ---------------------------------------------------------------------------
__global__ __launch_bounds__(256) void k_T(
    const float* __restrict__ k, const float* __restrict__ v,
    const uint4* __restrict__ kCb, const uint4* __restrict__ eBb,
    const int* __restrict__ flag,
    float* __restrict__ Ppart, float* __restrict__ Gpart, float* __restrict__ Qpart,
    float* __restrict__ S2, float* __restrict__ colsum)
{
    const int t = threadIdx.x;
    const int lane = t & 63;
    const int w = t >> 6;
    const int dgrp = blockIdx.x & 31;
    const int cgrp = blockIdx.x >> 5;          // 0..63
    const int d = dgrp * 64 + w * 16 + (lane & 15);
    const int rowoff = (lane >> 4) * 8;
    const int c0 = cgrp * 8;
    const int dnz = *flag;
    const int doS = (dgrp == 0);

    floatx4 accP = {0.f,0.f,0.f,0.f}, accG = {0.f,0.f,0.f,0.f};
    floatx4 accQ = {0.f,0.f,0.f,0.f}, accS = {0.f,0.f,0.f,0.f};
    float csl = 0.f;

    uint4 uKA = kCb[(size_t)c0 * 64 + lane];
    uint4 uEA = eBb[(size_t)c0 * 64 + lane];
    uint4 uKB = kCb[(size_t)(c0 + 1) * 64 + lane];
    uint4 uEB = eBb[(size_t)(c0 + 1) * 64 + lane];
    float knA[8], vnA[8], knB[8], vnB[8];
    {
        const float* kpA = k + ((size_t)(c0 * 32 + rowoff)) * DM + d;
        const float* vpA = v + ((size_t)(c0 * 32 + rowoff)) * DM + d;
        const float* kpB = kpA + (size_t)32 * DM;
        const float* vpB = vpA + (size_t)32 * DM;
        #pragma unroll
        for (int e = 0; e < 8; ++e) {
            knA[e] = kpA[(size_t)e * DM];
            vnA[e] = vpA[(size_t)e * DM];
            knB[e] = kpB[(size_t)e * DM];
            vnB[e] = vpB[(size_t)e * DM];
        }
        __builtin_amdgcn_sched_barrier(0);
    }

    #pragma unroll
    for (int cc = 0; cc < 8; cc += 2) {
        {
            U4S8 uK, uE, kf, vf;
            uK.u4 = uKA; uE.u4 = uEA;
            kf.u[0] = pk2(knA[0], knA[1]); kf.u[1] = pk2(knA[2], knA[3]);
            kf.u[2] = pk2(knA[4], knA[5]); kf.u[3] = pk2(knA[6], knA[7]);
            vf.u[0] = pk2(vnA[0], vnA[1]); vf.u[1] = pk2(vnA[2], vnA[3]);
            vf.u[2] = pk2(vnA[4], vnA[5]); vf.u[3] = pk2(vnA[6], vnA[7]);
            csl += knA[0] + knA[1] + knA[2] + knA[3]
                 + knA[4] + knA[5] + knA[6] + knA[7];

            const int cn = c0 + ((cc + 2 < 8) ? cc + 2 : cc);
            const float* kp = k + ((size_t)(cn * 32 + rowoff)) * DM + d;
            const float* vp = v + ((size_t)(cn * 32 + rowoff)) * DM + d;
            #pragma unroll
            for (int e = 0; e < 8; ++e) {
                knA[e] = kp[(size_t)e * DM];
                vnA[e] = vp[(size_t)e * DM];
            }
            uKA = kCb[(size_t)cn * 64 + lane];
            uEA = eBb[(size_t)cn * 64 + lane];
            __builtin_amdgcn_sched_barrier(0);   // pin refill issue here

            accP = __builtin_amdgcn_mfma_f32_16x16x32_bf16(uK.s8, vf.s8, accP, 0, 0, 0);
            accG = __builtin_amdgcn_mfma_f32_16x16x32_bf16(uE.s8, kf.s8, accG, 0, 0, 0);
            if (dnz)
                accQ = __builtin_amdgcn_mfma_f32_16x16x32_bf16(uK.s8, kf.s8, accQ, 0, 0, 0);
            if (doS)
                accS = __builtin_amdgcn_mfma_f32_16x16x32_bf16(uK.s8, uK.s8, accS, 0, 0, 0);
        }
        {
            U4S8 uK, uE, kf, vf;
            uK.u4 = uKB; uE.u4 = uEB;
            kf.u[0] = pk2(knB[0], knB[1]); kf.u[1] = pk2(knB[2], knB[3]);
            kf.u[2] = pk2(knB[4], knB[5]); kf.u[3] = pk2(knB[6], knB[7]);
            vf.u[0] = pk2(vnB[0], vnB[1]); vf.u[1] = pk2(vnB[2], vnB[3]);
            vf.u[2] = pk2(vnB[4], vnB[5]); vf.u[3] = pk2(vnB[6], vnB[7]);
            csl += knB[0] + knB[1] + knB[2] + knB[3]
                 + knB[4] + knB[5] + knB[6] + knB[7];

            const int cn = c0 + ((cc + 3 < 8) ? cc + 3 : cc + 1);
            const float* kp = k + ((size_t)(cn * 32 + rowoff)) * DM + d;
            const float* vp = v + ((size_t)(cn * 32 + rowoff)) * DM + d;
            #pragma unroll
            for (int e = 0; e < 8; ++e) {
                knB[e] = kp[(size_t)e * DM];
                vnB[e] = vp[(size_t)e * DM];
            }
            uKB = kCb[(size_t)cn * 64 + lane];
            uEB = eBb[(size_t)cn * 64 + lane];
            __builtin_amdgcn_sched_barrier(0);   // pin refill issue here

            accP = __builtin_amdgcn_mfma_f32_16x16x32_bf16(uK.s8, vf.s8, accP, 0, 0, 0);
            accG = __builtin_amdgcn_mfma_f32_16x16x32_bf16(uE.s8, kf.s8, accG, 0, 0, 0);
            if (dnz)
                accQ = __builtin_amdgcn_mfma_f32_16x16x32_bf16(uK.s8, kf.s8, accQ, 0, 0, 0);
            if (doS)
                accS = __builtin_amdgcn_mfma_f32_16x16x32_bf16(uK.s8, uK.s8, accS, 0, 0, 0);
        }
    }

    const int r0 = (lane >> 4) * 4;
    const size_t o = ((size_t)cgrp * DM + d) * RK + r0;
    __builtin_nontemporal_store(accP, (floatx4*)(Ppart + o));
    __builtin_nontemporal_store(accG, (floatx4*)(Gpart + o));
    if (dnz)
        __builtin_nontemporal_store(accQ, (floatx4*)(Qpart + o));

    if (doS && w == 0) {
        #pragma unroll
        for (int j = 0; j < 4; ++j)
            atomicAdd(S2 + (r0 + j) * RK + (lane & 15), accS[j]);
    }
    csl += __shfl_xor(csl, 16);
    csl += __shfl_xor(csl, 32);
    if ((lane >> 4) == 0) atomicAdd(colsum + d, csl);
}

// ---------------------------------------------------------------------------
// k_ro: ro[n,d] = 0.1*kC[n,:].B[d,:] (+ k*D if flag). Runs LAST (ro region
// doubles as partial-scratch until k_update consumes it). NT stores.
// ---------------------------------------------------------------------------
__global__ __launch_bounds__(256) void k_ro(
    const float* __restrict__ k, const float* __restrict__ B,
    const float* __restrict__ Dd, const float* __restrict__ kC_g,
    const int* __restrict__ flag, float* __restrict__ ro)
{
    __shared__ float kCch[16 * 16];
    const int t = threadIdx.x;
    const int slab = blockIdx.x & 1;
    const int chunk = blockIdx.x >> 1;
    const int d0 = slab * 1024 + t * 4;
    const int row0 = chunk * 16;
    const int dnz = *flag;

    float Breg[4][16], Dreg[4];
    #pragma unroll
    for (int i = 0; i < 4; ++i) {
        #pragma unroll
        for (int q = 0; q < 4; ++q) {
            const float4 b4 = *(const float4*)(B + (size_t)(d0 + i) * RK + q * 4);
            Breg[i][q*4+0] = b4.x; Breg[i][q*4+1] = b4.y;
            Breg[i][q*4+2] = b4.z; Breg[i][q*4+3] = b4.w;
        }
        Dreg[i] = Dd[d0 + i];
    }
    if (t < 64) *(float4*)&kCch[t * 4] = *(const float4*)(kC_g + (size_t)row0 * RK + t * 4);
    __syncthreads();

    float4 k0 = make_float4(0.f,0.f,0.f,0.f), k1 = k0;
    if (dnz) {
        k0 = *(const float4*)(k + (size_t)row0 * DM + d0);
        k1 = *(const float4*)(k + (size_t)(row0 + 1) * DM + d0);
    }

    for (int rr = 0; rr < 16; ++rr) {
        const int n = row0 + rr;
        const float4 kc4 = k0;
        if (dnz) {
            const int np = row0 + ((rr + 2 < 16) ? rr + 2 : 15);
            k0 = k1; k1 = *(const float4*)(k + (size_t)np * DM + d0);
        }
        float kcr[16];
        #pragma unroll
        for (int q = 0; q < 4; ++q) {
            const float4 c4 = *(const float4*)&kCch[rr * 16 + q * 4];
            kcr[q*4+0] = c4.x; kcr[q*4+1] = c4.y; kcr[q*4+2] = c4.z; kcr[q*4+3] = c4.w;
        }
        floatx4 roa;
        const float ka4[4] = {kc4.x, kc4.y, kc4.z, kc4.w};
        #pragma unroll
        for (int i = 0; i < 4; ++i) {
            float s = 0.f;
            #pragma unroll
            for (int r = 0; r < 16; ++r) s += kcr[r] * Breg[i][r];
            roa[i] = SCALEc * s;
            if (dnz) roa[i] += ka4[i] * Dreg[i];
        }
        __builtin_nontemporal_store(roa, (floatx4*)(ro + (size_t)n * DM + d0));
    }
}

// ---------------------------------------------------------------------------
// k_ln: k_mean = colsum/N; h1 = LayerNorm(k_mean)*gamma + beta.
// ---------------------------------------------------------------------------
__global__ __launch_bounds__(256) void k_ln(
    const float* __restrict__ colsum,
    const float* __restrict__ gam, const float* __restrict__ bet,
    float* __restrict__ h1)
{
    __shared__ float red[256];
    __shared__ float mu_sh, var_sh;
    const int t = threadIdx.x;
    float x[8];
    float s = 0.f;
    #pragma unroll
    for (int i = 0; i < 8; ++i) {
        x[i] = colsum[t + 256 * i] * (1.0f / (float)NROWS);
        s += x[i];
    }
    red[t] = s; __syncthreads();
    for (int off = 128; off > 0; off >>= 1) {
        if (t < off) red[t] += red[t + off];
        __syncthreads();
    }
    if (t == 0) mu_sh = red[0] * (1.0f / (float)DM);
    __syncthreads();
    const float mu = mu_sh;
    float s2 = 0.f;
    #pragma unroll
    for (int i = 0; i < 8; ++i) { const float dd = x[i] - mu; s2 += dd * dd; }
    __syncthreads();
    red[t] = s2; __syncthreads();
    for (int off = 128; off > 0; off >>= 1) {
        if (t < off) red[t] += red[t + off];
        __syncthreads();
    }
    if (t == 0) var_sh = red[0] * (1.0f / (float)DM);
    __syncthreads();
    const float rstd = rsqrtf(var_sh + LNEPS);
    #pragma unroll
    for (int i = 0; i < 8; ++i) {
        const int d = t + 256 * i;
        h1[d] = (x[i] - mu) * rstd * gam[d] + bet[d];
    }
}

// ---------------------------------------------------------------------------
// k_gemv: h2[i] = silu(h1 . W1[i,:] + b1[i]). 512 blocks x 256 (wave/row).
// ---------------------------------------------------------------------------
__global__ __launch_bounds__(256) void k_gemv(
    const float* __restrict__ h1, const float* __restrict__ W1,
    const float* __restrict__ b1, float* __restrict__ h2)
{
    const int t = threadIdx.x;
    const int lane = t & 63;
    const int w = t >> 6;
    const int row = blockIdx.x * 4 + w;
    const float* wr = W1 + (size_t)row * DM;
    float s = 0.f;
    #pragma unroll
    for (int j = 0; j < 8; ++j) {
        const float4 a = *(const float4*)(wr + j * 256 + lane * 4);
        const float4 b = *(const float4*)(h1 + j * 256 + lane * 4);
        s += a.x * b.x + a.y * b.y + a.z * b.z + a.w * b.w;
    }
    #pragma unroll
    for (int off = 32; off > 0; off >>= 1) s += __shfl_down(s, off);
    if (lane == 0) {
        const float val = s + b1[row];
        h2[row] = val / (1.0f + expf(-val));
    }
}

// ---------------------------------------------------------------------------
// k_alpha: alpha = sigmoid(h2 . W2 + b2).
// ---------------------------------------------------------------------------
__global__ __launch_bounds__(256) void k_alpha(
    const float* __restrict__ h2, const float* __restrict__ W2,
    const float* __restrict__ b2,
    float* __restrict__ alpha_ws, float* __restrict__ out_alpha)
{
    __shared__ float red[256];
    const int t = threadIdx.x;
    float s = 0.f;
    for (int i = t; i < DM; i += 256) s += h2[i] * W2[i];
    red[t] = s; __syncthreads();
    for (int off = 128; off > 0; off >>= 1) {
        if (t < off) red[t] += red[t + off];
        __syncthreads();
    }
    if (t == 0) {
        const float logit = red[0] + b2[0];
        const float a = 1.0f / (1.0f + expf(-logit));
        alpha_ws[0] = a;
        out_alpha[0] = a;
    }
}

// ---------------------------------------------------------------------------
// k_update: sum 64 partials; G1 = P1 - 0.1*B@S2 - D o Q; grads, momentum,
// B/C update. 128 blocks x 256.
// ---------------------------------------------------------------------------
__global__ __launch_bounds__(256) void k_update(
    const float* __restrict__ B, const float* __restrict__ C,
    const float* __restrict__ Dd,
    const float* __restrict__ S_B, const float* __restrict__ S_C,
    const float* __restrict__ Ppart, const float* __restrict__ Gpart,
    const float* __restrict__ Qpart, const float* __restrict__ S2,
    const float* __restrict__ CtC, const float* __restrict__ BtB,
    const float* __restrict__ alpha_ws, const int* __restrict__ flag,
    float* __restrict__ outB, float* __restrict__ outC,
    float* __restrict__ outSB, float* __restrict__ outSC)
{
    const int idx = blockIdx.x * 256 + threadIdx.x;   // [0, 32768)
    const int d = idx >> 4, r = idx & 15;
    const float alpha = alpha_ws[0];
    const int dnz = *flag;

    float P1v = 0.f, G2v = 0.f, Qv = 0.f;
    const size_t SL = (size_t)DM * RK;
    for (int p = 0; p < 64; ++p) {
        P1v += Ppart[(size_t)p * SL + idx];
        G2v += Gpart[(size_t)p * SL + idx];
    }
    if (dnz)
        for (int p = 0; p < 64; ++p) Qv += Qpart[(size_t)p * SL + idx];

    float Brow[16], Crow[16];
    #pragma unroll
    for (int q = 0; q < 4; ++q) {
        const float4 b4 = *(const float4*)(B + (size_t)d * RK + q * 4);
        const float4 c4 = *(const float4*)(C + (size_t)d * RK + q * 4);
        Brow[q*4+0] = b4.x; Brow[q*4+1] = b4.y; Brow[q*4+2] = b4.z; Brow[q*4+3] = b4.w;
        Crow[q*4+0] = c4.x; Crow[q*4+1] = c4.y; Crow[q*4+2] = c4.z; Crow[q*4+3] = c4.w;
    }
    float bc = 0.f, cb = 0.f, bs2 = 0.f;
    #pragma unroll
    for (int a = 0; a < 16; ++a) {
        bc  += Brow[a] * CtC[a * RK + r];
        cb  += Crow[a] * BtB[a * RK + r];
        bs2 += Brow[a] * S2[a * RK + r];
    }
    const float Ddv = Dd[d];
    const float invN = 1.0f / (float)NROWS;
    const float G1v = P1v - SCALEc * bs2 - Ddv * Qv;
    const float gradB = -G1v * invN + L2c * (SCALEc * bc + Ddv * Crow[r]);
    const float gradC = -G2v * invN + L2c * (SCALEc * cb + Ddv * Brow[r]);
    const float sB = MOMc * S_B[idx] - LRc * gradB;
    const float sC = MOMc * S_C[idx] - LRc * gradC;
    outSB[idx] = sB;
    outSC[idx] = sC;
    outB[idx] = (1.0f - alpha) * B[idx] + sB;
    outC[idx] = (1.0f - alpha) * C[idx] + sC;
}

// ---------------------------------------------------------------------------
extern "C" void kernel_launch(void* const* d_in, const int* in_sizes, int n_in,
                              void* d_out, int out_size, void* d_ws, size_t ws_size,
                              hipStream_t stream)
{
    const float* k   = (const float*)d_in[0];
    const float* v   = (const float*)d_in[1];
    const float* B   = (const float*)d_in[2];
    const float* C   = (const float*)d_in[3];
    const float* Dd  = (const float*)d_in[4];
    const float* S_B = (const float*)d_in[5];
    const float* S_C = (const float*)d_in[6];
    const float* gam = (const float*)d_in[7];
    const float* bet = (const float*)d_in[8];
    const float* W1  = (const float*)d_in[9];
    const float* b1  = (const float*)d_in[10];
    const float* W2  = (const float*)d_in[11];
    const float* b2  = (const float*)d_in[12];

    float* out      = (float*)d_out;
    float* ro       = out;                                  // [N, D] (written LAST)
    float* outB     = out + (size_t)NROWS * DM;
    float* outC     = outB + (size_t)DM * RK;
    float* outSB    = outC + (size_t)DM * RK;
    float* outSC    = outSB + (size_t)DM * RK;
    float* outAlpha = outSC + (size_t)DM * RK;

    // partial slabs live in the (not-yet-written) ro region: 64 x 32768 each
    float* Ppart = ro;                                      // 2,097,152 floats
    float* Gpart = Ppart + (size_t)64 * DM * RK;            // 2,097,152
    float* Qpart = Gpart + (size_t)64 * DM * RK;            // 2,097,152 (24 MB)

    float* ws = (float*)d_ws;
    float* kC_g   = ws;                                     // 262144
    float* vB_g   = kC_g + (size_t)NROWS * RK;              // 262144
    float* eB_g   = vB_g + (size_t)NROWS * RK;              // 262144 (kDB -> errB)
    float* S2     = eB_g + (size_t)NROWS * RK;              // 256 -- zero start
    float* CtC    = S2 + 256;                               // 256
    float* BtB    = CtC + 256;                              // 256
    float* colsum = BtB + 256;                              // 2048 -- zero end
    float* h1     = colsum + DM;                            // 2048
    float* h2     = h1 + DM;                                // 2048
    uint4* Cpk    = (uint4*)(h2 + DM);                      // 4096 uint4
    uint4* Bpk    = Cpk + 4096;
    uint4* DBpk   = Bpk + 4096;
    uint4* kCb    = DBpk + 4096;                            // 32768 uint4
    uint4* eBb    = kCb + 32768;                            // 32768 uint4
    float* alphaW = (float*)(eBb + 32768);
    int*   flag   = (int*)(alphaW + 1);

    // zero only S2/CtC/BtB/colsum: 2816 floats
    hipMemsetAsync(S2, 0, (size_t)2816 * sizeof(float), stream);

    hipLaunchKernelGGL(k_prep, dim3(33), dim3(256), 0, stream,
                       B, C, Dd, BtB, CtC, Cpk, Bpk, DBpk, flag);
    hipLaunchKernelGGL(k_A, dim3(1024), dim3(256), 0, stream,
                       k, v, Cpk, Bpk, DBpk, flag, kC_g, vB_g, eB_g);
    hipLaunchKernelGGL(k_mid, dim3(64), dim3(256), 0, stream,
                       kC_g, vB_g, eB_g, BtB, flag);
    hipLaunchKernelGGL(k_pack, dim3(128), dim3(256), 0, stream,
                       kC_g, eB_g, kCb, eBb);
    hipLaunchKernelGGL(k_T, dim3(2048), dim3(256), 0, stream,
                       k, v, kCb, eBb, flag, Ppart, Gpart, Qpart, S2, colsum);
    hipLaunchKernelGGL(k_ln, dim3(1), dim3(256), 0, stream, colsum, gam, bet, h1);
    hipLaunchKernelGGL(k_gemv, dim3(512), dim3(256), 0, stream, h1, W1, b1, h2);
    hipLaunchKernelGGL(k_alpha, dim3(1), dim3(256), 0, stream, h2, W2, b2, alphaW, outAlpha);
    hipLaunchKernelGGL(k_update, dim3(128), dim3(256), 0, stream,
                       B, C, Dd, S_B, S_C, Ppart, Gpart, Qpart, S2, CtC, BtB,
                       alphaW, flag, outB, outC, outSB, outSC);
    hipLaunchKernelGGL(k_ro, dim3(2048), dim3(256), 0, stream,
                       k, B, Dd, kC_g, flag, ro);
}